// Round 1
// baseline (943.802 us; speedup 1.0000x reference)
//
#include <hip/hip_runtime.h>
#include <math.h>

#define D 128

// ---------------- GEMM: xl = x@Wl+bl, xr = x@Wr+br ----------------
// block = 256 threads, 32 rows x 128 cols per block; W staged in LDS (64KB),
// x rows in LDS (16KB). Each thread computes a 4x4 sub-tile.
__global__ __launch_bounds__(256) void gemm_k(const float* __restrict__ x,
    const float* __restrict__ Wl, const float* __restrict__ bl,
    const float* __restrict__ Wr, const float* __restrict__ br,
    float* __restrict__ xl, float* __restrict__ xr, int n)
{
    __shared__ float Ws[128 * 128];   // W[k][c], 64KB
    __shared__ float xs[32 * 128];    // 16KB
    const int t = threadIdx.x;
    const float* W   = blockIdx.y ? Wr : Wl;
    const float* bia = blockIdx.y ? br : bl;
    float* out       = blockIdx.y ? xr : xl;

    const float4* W4 = (const float4*)W;
    float4* Ws4 = (float4*)Ws;
#pragma unroll
    for (int i = 0; i < 16; i++) Ws4[t + 256 * i] = W4[t + 256 * i];

    const int row0 = blockIdx.x * 32;
    const int avail = n - row0;                  // >= 1
    const float4* x4 = (const float4*)(x + (size_t)row0 * D);
    float4* xs4 = (float4*)xs;
#pragma unroll
    for (int i = 0; i < 4; i++) {
        int idx = t + 256 * i;                   // float4 index, 32 per row
        if ((idx >> 5) < avail) xs4[idx] = x4[idx];
        else xs4[idx] = make_float4(0.f, 0.f, 0.f, 0.f);
    }
    __syncthreads();

    const int tc = (t & 31) * 4;                 // col base
    const int tr = (t >> 5) * 4;                 // row base
    float acc[4][4];
#pragma unroll
    for (int i = 0; i < 4; i++)
#pragma unroll
        for (int j = 0; j < 4; j++) acc[i][j] = 0.f;

    for (int k = 0; k < 128; k += 4) {
        float4 xv[4];
#pragma unroll
        for (int i = 0; i < 4; i++) xv[i] = *(const float4*)&xs[(tr + i) * 128 + k];
#pragma unroll
        for (int kk = 0; kk < 4; kk++) {
            float4 wv = *(const float4*)&Ws[(k + kk) * 128 + tc];
#pragma unroll
            for (int i = 0; i < 4; i++) {
                float xvk = kk == 0 ? xv[i].x : kk == 1 ? xv[i].y : kk == 2 ? xv[i].z : xv[i].w;
                acc[i][0] += xvk * wv.x;
                acc[i][1] += xvk * wv.y;
                acc[i][2] += xvk * wv.z;
                acc[i][3] += xvk * wv.w;
            }
        }
    }

    float4 bv = *(const float4*)&bia[tc];
#pragma unroll
    for (int i = 0; i < 4; i++) {
        int row = row0 + tr + i;
        if (row < n) {
            float4 o = make_float4(acc[i][0] + bv.x, acc[i][1] + bv.y,
                                   acc[i][2] + bv.z, acc[i][3] + bv.w);
            *(float4*)&out[(size_t)row * D + tc] = o;
        }
    }
}

// order-preserving float->uint encoding (monotone; -inf sentinel == 0)
__device__ __forceinline__ unsigned int enc_f(float f) {
    unsigned int u = __float_as_uint(f);
    return (u & 0x80000000u) ? ~u : (u | 0x80000000u);
}
__device__ __forceinline__ float dec_f(unsigned int u) {
    unsigned int b = (u & 0x80000000u) ? (u ^ 0x80000000u) : ~u;
    return __uint_as_float(b);
}

// ---------------- edge logits + segment max ----------------
// one 64-lane wave per edge; lane covers 2 features
__global__ __launch_bounds__(256) void edge_logits_k(const float* __restrict__ xl,
    const float* __restrict__ xr, const int* __restrict__ ei,
    const float* __restrict__ ea, const float* __restrict__ We,
    const float* __restrict__ att, float* __restrict__ logits,
    unsigned int* __restrict__ nodemax, int E)
{
    int wave = threadIdx.x >> 6;
    int lane = threadIdx.x & 63;
    int e = blockIdx.x * 4 + wave;
    if (e >= E) return;
    int src = ei[e];
    int dst = ei[E + e];
    float eav = ea[e];
    int c = lane * 2;
    float2 a  = *(const float2*)(xl + (size_t)src * D + c);
    float2 b  = *(const float2*)(xr + (size_t)dst * D + c);
    float2 w  = *(const float2*)(We + c);
    float2 at = *(const float2*)(att + c);
    float m0 = a.x + b.x + eav * w.x;
    float m1 = a.y + b.y + eav * w.y;
    m0 = m0 > 0.f ? m0 : 0.2f * m0;
    m1 = m1 > 0.f ? m1 : 0.2f * m1;
    float p = m0 * at.x + m1 * at.y;
#pragma unroll
    for (int off = 32; off > 0; off >>= 1) p += __shfl_xor(p, off);
    if (lane == 0) {
        logits[e] = p;
        atomicMax(&nodemax[dst], enc_f(p));
    }
}

// ---------------- exp + segment denominator ----------------
__global__ __launch_bounds__(256) void edge_exp_k(const float* __restrict__ logits,
    const int* __restrict__ ei, const unsigned int* __restrict__ nodemax,
    float* __restrict__ ex, float* __restrict__ den, int E)
{
    int e = blockIdx.x * blockDim.x + threadIdx.x;
    if (e >= E) return;
    int dst = ei[E + e];
    float mx = dec_f(nodemax[dst]);
    float v = expf(logits[e] - mx);
    ex[e] = v;
    unsafeAtomicAdd(&den[dst], v);
}

// ---------------- weighted scatter-accumulate ----------------
__global__ __launch_bounds__(256) void edge_agg_k(const float* __restrict__ xl,
    const int* __restrict__ ei, const float* __restrict__ ex,
    const float* __restrict__ den, float* __restrict__ out, int E)
{
    int wave = threadIdx.x >> 6;
    int lane = threadIdx.x & 63;
    int e = blockIdx.x * 4 + wave;
    if (e >= E) return;
    int src = ei[e];
    int dst = ei[E + e];
    float alpha = ex[e] / (den[dst] + 1e-16f);
    int c = lane * 2;
    float2 v = *(const float2*)(xl + (size_t)src * D + c);
    unsafeAtomicAdd(&out[(size_t)dst * D + c],     alpha * v.x);
    unsafeAtomicAdd(&out[(size_t)dst * D + c + 1], alpha * v.y);
}

// ---------------- residual + GELU(erf) + BN stats ----------------
__global__ __launch_bounds__(256) void gelu_stats_k(const float* __restrict__ x,
    const float* __restrict__ bias, float* __restrict__ h,
    float* __restrict__ colsum, float* __restrict__ colsq, int total4)
{
    __shared__ float s_sum[128], s_sq[128];
    int t = threadIdx.x;
    if (t < 128) { s_sum[t] = 0.f; s_sq[t] = 0.f; }
    __syncthreads();
    int i4 = blockIdx.x * blockDim.x + t;
    if (i4 < total4) {
        float4 g4 = ((const float4*)h)[i4];
        float4 xv = ((const float4*)x)[i4];
        int c0 = (i4 & 31) * 4;
        float gv[4] = {g4.x, g4.y, g4.z, g4.w};
        float xa[4] = {xv.x, xv.y, xv.z, xv.w};
        float res[4];
#pragma unroll
        for (int j = 0; j < 4; j++) {
            float hv = xa[j] + gv[j] + bias[c0 + j];
            float ge = 0.5f * hv * (1.f + erff(hv * 0.70710678118654752f));
            res[j] = ge;
            atomicAdd(&s_sum[c0 + j], ge);
            atomicAdd(&s_sq[c0 + j], ge * ge);
        }
        ((float4*)h)[i4] = make_float4(res[0], res[1], res[2], res[3]);
    }
    __syncthreads();
    if (t < 128) {
        unsafeAtomicAdd(&colsum[t], s_sum[t]);
        unsafeAtomicAdd(&colsq[t], s_sq[t]);
    }
}

// ---------------- BN parameter fold ----------------
__global__ void bn_params_k(const float* __restrict__ colsum, const float* __restrict__ colsq,
    const float* __restrict__ gamma, const float* __restrict__ beta,
    float* __restrict__ ab, float n)
{
    int c = threadIdx.x;
    float mean = colsum[c] / n;
    float var = colsq[c] / n - mean * mean;
    float a = rsqrtf(var + 1e-5f) * gamma[c];
    ab[c] = a;
    ab[c + 128] = beta[c] - mean * a;
}

// ---------------- BN apply ----------------
__global__ __launch_bounds__(256) void bn_apply_k(float* __restrict__ h,
    const float* __restrict__ ab, int total4)
{
    int i4 = blockIdx.x * blockDim.x + threadIdx.x;
    if (i4 >= total4) return;
    int cg = i4 & 31;
    float4 v = ((const float4*)h)[i4];
    float4 a = ((const float4*)ab)[cg];
    float4 b = ((const float4*)(ab + 128))[cg];
    ((float4*)h)[i4] = make_float4(v.x * a.x + b.x, v.y * a.y + b.y,
                                   v.z * a.z + b.z, v.w * a.w + b.w);
}

extern "C" void kernel_launch(void* const* d_in, const int* in_sizes, int n_in,
                              void* d_out, int out_size, void* d_ws, size_t ws_size,
                              hipStream_t stream)
{
    const float* x    = (const float*)d_in[0];
    const int*   ei   = (const int*)d_in[1];
    const float* ea   = (const float*)d_in[2];
    const float* Wl   = (const float*)d_in[3];
    const float* bl   = (const float*)d_in[4];
    const float* Wr   = (const float*)d_in[5];
    const float* br   = (const float*)d_in[6];
    const float* We   = (const float*)d_in[7];
    const float* att  = (const float*)d_in[8];
    const float* bias = (const float*)d_in[9];
    const float* gamma= (const float*)d_in[10];
    const float* beta = (const float*)d_in[11];
    float* out = (float*)d_out;

    const int n = in_sizes[0] / D;
    const int E = in_sizes[1] / 2;

    float* ws = (float*)d_ws;
    float* xl = ws;                                   // n*D
    float* xr = xl + (size_t)n * D;                   // n*D
    float* logits = xr + (size_t)n * D;               // E
    float* ex = logits + E;                           // E
    unsigned int* nodemax = (unsigned int*)(ex + E);  // n
    float* den = (float*)(nodemax + n);               // n
    float* colsum = den + n;                          // 128
    float* colsq = colsum + D;                        // 128
    float* ab = colsq + D;                            // 256

    hipMemsetAsync(nodemax, 0, (size_t)n * 4, stream);       // enc(-inf) == 0
    hipMemsetAsync(den, 0, (size_t)n * 4, stream);
    hipMemsetAsync(colsum, 0, 2 * D * 4, stream);
    hipMemsetAsync(out, 0, (size_t)n * D * 4, stream);

    dim3 gg((n + 31) / 32, 2);
    gemm_k<<<gg, 256, 0, stream>>>(x, Wl, bl, Wr, br, xl, xr, n);
    edge_logits_k<<<(E + 3) / 4, 256, 0, stream>>>(xl, xr, ei, ea, We, att, logits, nodemax, E);
    edge_exp_k<<<(E + 255) / 256, 256, 0, stream>>>(logits, ei, nodemax, ex, den, E);
    edge_agg_k<<<(E + 3) / 4, 256, 0, stream>>>(xl, ei, ex, den, out, E);
    const int total4 = (n * D) / 4;
    gelu_stats_k<<<(total4 + 255) / 256, 256, 0, stream>>>(x, bias, out, colsum, colsq, total4);
    bn_params_k<<<1, 128, 0, stream>>>(colsum, colsq, gamma, beta, ab, (float)n);
    bn_apply_k<<<(total4 + 255) / 256, 256, 0, stream>>>(out, ab, total4);
}

// Round 2
// 543.475 us; speedup vs baseline: 1.7366x; 1.7366x over previous
//
#include <hip/hip_runtime.h>
#include <math.h>

#define D 128

// ---------------- GEMM: xl = x@Wl+bl, xr = x@Wr+br ----------------
__global__ __launch_bounds__(256) void gemm_k(const float* __restrict__ x,
    const float* __restrict__ Wl, const float* __restrict__ bl,
    const float* __restrict__ Wr, const float* __restrict__ br,
    float* __restrict__ xl, float* __restrict__ xr, int n)
{
    __shared__ float Ws[128 * 128];   // W[k][c], 64KB
    __shared__ float xs[32 * 128];    // 16KB
    const int t = threadIdx.x;
    const float* W   = blockIdx.y ? Wr : Wl;
    const float* bia = blockIdx.y ? br : bl;
    float* out       = blockIdx.y ? xr : xl;

    const float4* W4 = (const float4*)W;
    float4* Ws4 = (float4*)Ws;
#pragma unroll
    for (int i = 0; i < 16; i++) Ws4[t + 256 * i] = W4[t + 256 * i];

    const int row0 = blockIdx.x * 32;
    const int avail = n - row0;
    const float4* x4 = (const float4*)(x + (size_t)row0 * D);
    float4* xs4 = (float4*)xs;
#pragma unroll
    for (int i = 0; i < 4; i++) {
        int idx = t + 256 * i;
        if ((idx >> 5) < avail) xs4[idx] = x4[idx];
        else xs4[idx] = make_float4(0.f, 0.f, 0.f, 0.f);
    }
    __syncthreads();

    const int tc = (t & 31) * 4;
    const int tr = (t >> 5) * 4;
    float acc[4][4];
#pragma unroll
    for (int i = 0; i < 4; i++)
#pragma unroll
        for (int j = 0; j < 4; j++) acc[i][j] = 0.f;

    for (int k = 0; k < 128; k += 4) {
        float4 xv[4];
#pragma unroll
        for (int i = 0; i < 4; i++) xv[i] = *(const float4*)&xs[(tr + i) * 128 + k];
#pragma unroll
        for (int kk = 0; kk < 4; kk++) {
            float4 wv = *(const float4*)&Ws[(k + kk) * 128 + tc];
#pragma unroll
            for (int i = 0; i < 4; i++) {
                float xvk = kk == 0 ? xv[i].x : kk == 1 ? xv[i].y : kk == 2 ? xv[i].z : xv[i].w;
                acc[i][0] += xvk * wv.x;
                acc[i][1] += xvk * wv.y;
                acc[i][2] += xvk * wv.z;
                acc[i][3] += xvk * wv.w;
            }
        }
    }

    float4 bv = *(const float4*)&bia[tc];
#pragma unroll
    for (int i = 0; i < 4; i++) {
        int row = row0 + tr + i;
        if (row < n) {
            float4 o = make_float4(acc[i][0] + bv.x, acc[i][1] + bv.y,
                                   acc[i][2] + bv.z, acc[i][3] + bv.w);
            *(float4*)&out[(size_t)row * D + tc] = o;
        }
    }
}

// ---------------- CSR build: histogram ----------------
__global__ __launch_bounds__(256) void hist_k(const int* __restrict__ ei,
    int* __restrict__ deg, int E)
{
    int e = blockIdx.x * blockDim.x + threadIdx.x;
    if (e < E) atomicAdd(&deg[ei[E + e]], 1);
}

// ---------------- CSR build: single-block looped exclusive scan ----------------
// reads deg[], writes rowptr[] (n+1) and rewrites deg[] as the scatter cursor
__global__ __launch_bounds__(1024) void scan_k(int* __restrict__ deg,
    int* __restrict__ rowptr, int n)
{
    __shared__ int s[1024];
    const int t = threadIdx.x;
    int run = 0;
    for (int base = 0; base < n; base += 1024) {
        int i = base + t;
        int v = (i < n) ? deg[i] : 0;
        s[t] = v;
        __syncthreads();
        for (int off = 1; off < 1024; off <<= 1) {
            int add = (t >= off) ? s[t - off] : 0;
            __syncthreads();
            s[t] += add;
            __syncthreads();
        }
        if (i < n) {
            int ex = run + s[t] - v;
            rowptr[i] = ex;
            deg[i] = ex;      // cursor
        }
        int tot = s[1023];
        __syncthreads();
        run += tot;
    }
    if (t == 0) rowptr[n] = run;
}

// ---------------- CSR build: scatter edges into dst-grouped order ----------------
__global__ __launch_bounds__(256) void scatter_k(const int* __restrict__ ei,
    const float* __restrict__ ea, int* __restrict__ cursor,
    int* __restrict__ srcs, float* __restrict__ eas, int E)
{
    int e = blockIdx.x * blockDim.x + threadIdx.x;
    if (e >= E) return;
    int dst = ei[E + e];
    int pos = atomicAdd(&cursor[dst], 1);
    srcs[pos] = ei[e];
    eas[pos] = ea[e];
}

// ---------------- fused edge logits + online softmax + aggregate ----------------
// one 64-lane wave per destination node; lane owns 2 feature columns
__global__ __launch_bounds__(256) void agg_k(const float* __restrict__ xl,
    const float* __restrict__ xr, const int* __restrict__ rowptr,
    const int* __restrict__ srcs, const float* __restrict__ eas,
    const float* __restrict__ We, const float* __restrict__ att,
    float* __restrict__ out, int n)
{
    int wave = threadIdx.x >> 6;
    int lane = threadIdx.x & 63;
    int v = blockIdx.x * 4 + wave;
    if (v >= n) return;
    int beg = rowptr[v];
    int end = rowptr[v + 1];
    int c = lane * 2;
    float2 xrv = *(const float2*)(xr + (size_t)v * D + c);
    float2 wev = *(const float2*)(We + c);
    float2 atv = *(const float2*)(att + c);

    float m = -INFINITY, s = 0.f, acc0 = 0.f, acc1 = 0.f;
    for (int j = beg; j < end; j++) {
        int src = srcs[j];
        float eav = eas[j];
        float2 xv = *(const float2*)(xl + (size_t)src * D + c);
        float m0 = xv.x + xrv.x + eav * wev.x;
        float m1 = xv.y + xrv.y + eav * wev.y;
        m0 = m0 > 0.f ? m0 : 0.2f * m0;
        m1 = m1 > 0.f ? m1 : 0.2f * m1;
        float p = m0 * atv.x + m1 * atv.y;
#pragma unroll
        for (int off = 32; off > 0; off >>= 1) p += __shfl_xor(p, off);
        float mn = fmaxf(m, p);
        float sc = __expf(m - mn);   // first iter: exp(-inf)=0
        float w  = __expf(p - mn);
        s = s * sc + w;
        acc0 = acc0 * sc + w * xv.x;
        acc1 = acc1 * sc + w * xv.y;
        m = mn;
    }
    float inv = 1.f / (s + 1e-16f);   // deg==0 -> acc=0 -> out=0
    *(float2*)(out + (size_t)v * D + c) = make_float2(acc0 * inv, acc1 * inv);
}

// ---------------- residual + GELU(erf) + BN stats ----------------
__global__ __launch_bounds__(256) void gelu_stats_k(const float* __restrict__ x,
    const float* __restrict__ bias, float* __restrict__ h,
    float* __restrict__ colsum, float* __restrict__ colsq, int total4)
{
    __shared__ float s_sum[128], s_sq[128];
    int t = threadIdx.x;
    if (t < 128) { s_sum[t] = 0.f; s_sq[t] = 0.f; }
    __syncthreads();
    int i4 = blockIdx.x * blockDim.x + t;
    if (i4 < total4) {
        float4 g4 = ((const float4*)h)[i4];
        float4 xv = ((const float4*)x)[i4];
        int c0 = (i4 & 31) * 4;
        float gv[4] = {g4.x, g4.y, g4.z, g4.w};
        float xa[4] = {xv.x, xv.y, xv.z, xv.w};
        float res[4];
#pragma unroll
        for (int j = 0; j < 4; j++) {
            float hv = xa[j] + gv[j] + bias[c0 + j];
            float ge = 0.5f * hv * (1.f + erff(hv * 0.70710678118654752f));
            res[j] = ge;
            atomicAdd(&s_sum[c0 + j], ge);
            atomicAdd(&s_sq[c0 + j], ge * ge);
        }
        ((float4*)h)[i4] = make_float4(res[0], res[1], res[2], res[3]);
    }
    __syncthreads();
    if (t < 128) {
        unsafeAtomicAdd(&colsum[t], s_sum[t]);
        unsafeAtomicAdd(&colsq[t], s_sq[t]);
    }
}

// ---------------- BN parameter fold ----------------
__global__ void bn_params_k(const float* __restrict__ colsum, const float* __restrict__ colsq,
    const float* __restrict__ gamma, const float* __restrict__ beta,
    float* __restrict__ ab, float n)
{
    int c = threadIdx.x;
    float mean = colsum[c] / n;
    float var = colsq[c] / n - mean * mean;
    float a = rsqrtf(var + 1e-5f) * gamma[c];
    ab[c] = a;
    ab[c + 128] = beta[c] - mean * a;
}

// ---------------- BN apply ----------------
__global__ __launch_bounds__(256) void bn_apply_k(float* __restrict__ h,
    const float* __restrict__ ab, int total4)
{
    int i4 = blockIdx.x * blockDim.x + threadIdx.x;
    if (i4 >= total4) return;
    int cg = i4 & 31;
    float4 v = ((const float4*)h)[i4];
    float4 a = ((const float4*)ab)[cg];
    float4 b = ((const float4*)(ab + 128))[cg];
    ((float4*)h)[i4] = make_float4(v.x * a.x + b.x, v.y * a.y + b.y,
                                   v.z * a.z + b.z, v.w * a.w + b.w);
}

extern "C" void kernel_launch(void* const* d_in, const int* in_sizes, int n_in,
                              void* d_out, int out_size, void* d_ws, size_t ws_size,
                              hipStream_t stream)
{
    const float* x    = (const float*)d_in[0];
    const int*   ei   = (const int*)d_in[1];
    const float* ea   = (const float*)d_in[2];
    const float* Wl   = (const float*)d_in[3];
    const float* bl   = (const float*)d_in[4];
    const float* Wr   = (const float*)d_in[5];
    const float* br   = (const float*)d_in[6];
    const float* We   = (const float*)d_in[7];
    const float* att  = (const float*)d_in[8];
    const float* bias = (const float*)d_in[9];
    const float* gamma= (const float*)d_in[10];
    const float* beta = (const float*)d_in[11];
    float* out = (float*)d_out;

    const int n = in_sizes[0] / D;
    const int E = in_sizes[1] / 2;

    float* ws = (float*)d_ws;
    float* xl = ws;                                   // n*D
    float* xr = xl + (size_t)n * D;                   // n*D
    int* deg = (int*)(xr + (size_t)n * D);            // n   (becomes cursor)
    int* rowptr = deg + n;                            // n+1
    int* srcs = rowptr + n + 1;                       // E
    float* eas = (float*)(srcs + E);                  // E
    float* colsum = eas + E;                          // 128
    float* colsq = colsum + D;                        // 128
    float* ab = colsq + D;                            // 256

    hipMemsetAsync(deg, 0, (size_t)n * 4, stream);
    hipMemsetAsync(colsum, 0, 2 * D * 4, stream);

    dim3 gg((n + 31) / 32, 2);
    gemm_k<<<gg, 256, 0, stream>>>(x, Wl, bl, Wr, br, xl, xr, n);
    hist_k<<<(E + 255) / 256, 256, 0, stream>>>(ei, deg, E);
    scan_k<<<1, 1024, 0, stream>>>(deg, rowptr, n);
    scatter_k<<<(E + 255) / 256, 256, 0, stream>>>(ei, ea, deg, srcs, eas, E);
    agg_k<<<(n + 3) / 4, 256, 0, stream>>>(xl, xr, rowptr, srcs, eas, We, att, out, n);
    const int total4 = (n * D) / 4;
    gelu_stats_k<<<(total4 + 255) / 256, 256, 0, stream>>>(x, bias, out, colsum, colsq, total4);
    bn_params_k<<<1, 128, 0, stream>>>(colsum, colsq, gamma, beta, ab, (float)n);
    bn_apply_k<<<(total4 + 255) / 256, 256, 0, stream>>>(out, ab, total4);
}

// Round 3
// 369.780 us; speedup vs baseline: 2.5523x; 1.4697x over previous
//
#include <hip/hip_runtime.h>
#include <math.h>

#define D 128
#define STATS_BLOCKS 512

// ---------------- GEMM: xl = x@Wl+bl, xr = x@Wr+br ----------------
__global__ __launch_bounds__(256) void gemm_k(const float* __restrict__ x,
    const float* __restrict__ Wl, const float* __restrict__ bl,
    const float* __restrict__ Wr, const float* __restrict__ br,
    float* __restrict__ xl, float* __restrict__ xr, int n)
{
    __shared__ float Ws[128 * 128];   // W[k][c], 64KB
    __shared__ float xs[32 * 128];    // 16KB
    const int t = threadIdx.x;
    const float* W   = blockIdx.y ? Wr : Wl;
    const float* bia = blockIdx.y ? br : bl;
    float* out       = blockIdx.y ? xr : xl;

    const float4* W4 = (const float4*)W;
    float4* Ws4 = (float4*)Ws;
#pragma unroll
    for (int i = 0; i < 16; i++) Ws4[t + 256 * i] = W4[t + 256 * i];

    const int row0 = blockIdx.x * 32;
    const int avail = n - row0;
    const float4* x4 = (const float4*)(x + (size_t)row0 * D);
    float4* xs4 = (float4*)xs;
#pragma unroll
    for (int i = 0; i < 4; i++) {
        int idx = t + 256 * i;
        if ((idx >> 5) < avail) xs4[idx] = x4[idx];
        else xs4[idx] = make_float4(0.f, 0.f, 0.f, 0.f);
    }
    __syncthreads();

    const int tc = (t & 31) * 4;
    const int tr = (t >> 5) * 4;
    float acc[4][4];
#pragma unroll
    for (int i = 0; i < 4; i++)
#pragma unroll
        for (int j = 0; j < 4; j++) acc[i][j] = 0.f;

    for (int k = 0; k < 128; k += 4) {
        float4 xv[4];
#pragma unroll
        for (int i = 0; i < 4; i++) xv[i] = *(const float4*)&xs[(tr + i) * 128 + k];
#pragma unroll
        for (int kk = 0; kk < 4; kk++) {
            float4 wv = *(const float4*)&Ws[(k + kk) * 128 + tc];
#pragma unroll
            for (int i = 0; i < 4; i++) {
                float xvk = kk == 0 ? xv[i].x : kk == 1 ? xv[i].y : kk == 2 ? xv[i].z : xv[i].w;
                acc[i][0] += xvk * wv.x;
                acc[i][1] += xvk * wv.y;
                acc[i][2] += xvk * wv.z;
                acc[i][3] += xvk * wv.w;
            }
        }
    }

    float4 bv = *(const float4*)&bia[tc];
#pragma unroll
    for (int i = 0; i < 4; i++) {
        int row = row0 + tr + i;
        if (row < n) {
            float4 o = make_float4(acc[i][0] + bv.x, acc[i][1] + bv.y,
                                   acc[i][2] + bv.z, acc[i][3] + bv.w);
            *(float4*)&out[(size_t)row * D + tc] = o;
        }
    }
}

// ---------------- CSR build: histogram ----------------
__global__ __launch_bounds__(256) void hist_k(const int* __restrict__ ei,
    int* __restrict__ deg, int E)
{
    int e = blockIdx.x * blockDim.x + threadIdx.x;
    if (e < E) atomicAdd(&deg[ei[E + e]], 1);
}

// ---------------- CSR build: chunked single-block exclusive scan ----------------
// each thread owns a contiguous chunk; one wave-level scan over thread totals
__global__ __launch_bounds__(1024) void scan_k(int* __restrict__ deg,
    int* __restrict__ rowptr, int n)
{
    const int t = threadIdx.x;
    const int chunk = (n + 1023) >> 10;
    const int lo = t * chunk;
    const int hi = min(lo + chunk, n);
    int s = 0;
    for (int i = lo; i < hi; i++) s += deg[i];

    // inclusive scan of 1024 thread sums: wave scan + wave-offset scan
    const int lane = t & 63, w = t >> 6;       // 16 waves
    int v = s;
#pragma unroll
    for (int off = 1; off < 64; off <<= 1) {
        int u = __shfl_up(v, off);
        if (lane >= off) v += u;
    }
    __shared__ int wsum[16], woff[16];
    if (lane == 63) wsum[w] = v;
    __syncthreads();
    if (t < 16) {
        int xv = wsum[t];
#pragma unroll
        for (int off = 1; off < 16; off <<= 1) {
            int u = __shfl_up(xv, off);
            if (t >= off) xv += u;
        }
        woff[t] = xv;                           // inclusive wave prefix
    }
    __syncthreads();
    int run = v - s + (w > 0 ? woff[w - 1] : 0); // exclusive prefix for chunk
    for (int i = lo; i < hi; i++) {
        int d = deg[i];
        rowptr[i] = run;
        deg[i] = run;                            // scatter cursor
        run += d;
    }
    if (t == 1023) rowptr[n] = run;
}

// ---------------- CSR build: scatter edges into dst-grouped order ----------------
__global__ __launch_bounds__(256) void scatter_k(const int* __restrict__ ei,
    const float* __restrict__ ea, int* __restrict__ cursor,
    int* __restrict__ srcs, float* __restrict__ eas, int E)
{
    int e = blockIdx.x * blockDim.x + threadIdx.x;
    if (e >= E) return;
    int dst = ei[E + e];
    int pos = atomicAdd(&cursor[dst], 1);
    srcs[pos] = ei[e];
    eas[pos] = ea[e];
}

// ---------------- fused edge logits + online softmax + aggregate ----------------
// one 64-lane wave per destination node; lane owns 2 feature columns
__global__ __launch_bounds__(256) void agg_k(const float* __restrict__ xl,
    const float* __restrict__ xr, const int* __restrict__ rowptr,
    const int* __restrict__ srcs, const float* __restrict__ eas,
    const float* __restrict__ We, const float* __restrict__ att,
    float* __restrict__ out, int n)
{
    int wave = threadIdx.x >> 6;
    int lane = threadIdx.x & 63;
    int v = blockIdx.x * 4 + wave;
    if (v >= n) return;
    int beg = rowptr[v];
    int end = rowptr[v + 1];
    int c = lane * 2;
    float2 xrv = *(const float2*)(xr + (size_t)v * D + c);
    float2 wev = *(const float2*)(We + c);
    float2 atv = *(const float2*)(att + c);

    float m = -INFINITY, s = 0.f, acc0 = 0.f, acc1 = 0.f;
    for (int j = beg; j < end; j++) {
        int src = srcs[j];
        float eav = eas[j];
        float2 xv = *(const float2*)(xl + (size_t)src * D + c);
        float m0 = xv.x + xrv.x + eav * wev.x;
        float m1 = xv.y + xrv.y + eav * wev.y;
        m0 = m0 > 0.f ? m0 : 0.2f * m0;
        m1 = m1 > 0.f ? m1 : 0.2f * m1;
        float p = m0 * atv.x + m1 * atv.y;
#pragma unroll
        for (int off = 32; off > 0; off >>= 1) p += __shfl_xor(p, off);
        float mn = fmaxf(m, p);
        float sc = __expf(m - mn);   // first iter: exp(-inf)=0
        float w  = __expf(p - mn);
        s = s * sc + w;
        acc0 = acc0 * sc + w * xv.x;
        acc1 = acc1 * sc + w * xv.y;
        m = mn;
    }
    float inv = 1.f / (s + 1e-16f);   // deg==0 -> acc=0 -> out=0
    *(float2*)(out + (size_t)v * D + c) = make_float2(acc0 * inv, acc1 * inv);
}

// ---------------- residual + GELU(erf) + BN stats (atomic-free) ----------------
// fixed grid, grid-stride; thread's 4 columns invariant since stride % 32 == 0
__global__ __launch_bounds__(256) void gelu_stats_k(const float* __restrict__ x,
    const float* __restrict__ bias, float* __restrict__ h,
    float* __restrict__ partials, int total4)
{
    const int t = threadIdx.x;
    const int c0 = (t & 31) * 4;
    const float4 bv = *(const float4*)&bias[c0];
    float sum[4] = {0.f, 0.f, 0.f, 0.f}, sq[4] = {0.f, 0.f, 0.f, 0.f};
    const int stride = gridDim.x * blockDim.x;
    for (int i4 = blockIdx.x * blockDim.x + t; i4 < total4; i4 += stride) {
        float4 g4 = ((const float4*)h)[i4];
        float4 xv = ((const float4*)x)[i4];
        float hv[4] = {xv.x + g4.x + bv.x, xv.y + g4.y + bv.y,
                       xv.z + g4.z + bv.z, xv.w + g4.w + bv.w};
        float res[4];
#pragma unroll
        for (int j = 0; j < 4; j++) {
            float ge = 0.5f * hv[j] * (1.f + erff(hv[j] * 0.70710678118654752f));
            res[j] = ge;
            sum[j] += ge;
            sq[j] += ge * ge;
        }
        ((float4*)h)[i4] = make_float4(res[0], res[1], res[2], res[3]);
    }
    // block reduce: red[slot][column], slot = t>>5 (8 slots), no atomics
    __shared__ float red[8][128];
    const int slot = t >> 5;
#pragma unroll
    for (int j = 0; j < 4; j++) red[slot][c0 + j] = sum[j];
    __syncthreads();
    if (t < 128) {
        float tot = 0.f;
#pragma unroll
        for (int s2 = 0; s2 < 8; s2++) tot += red[s2][t];
        partials[(size_t)t * STATS_BLOCKS + blockIdx.x] = tot;
    }
    __syncthreads();
#pragma unroll
    for (int j = 0; j < 4; j++) red[slot][c0 + j] = sq[j];
    __syncthreads();
    if (t < 128) {
        float tot = 0.f;
#pragma unroll
        for (int s2 = 0; s2 < 8; s2++) tot += red[s2][t];
        partials[(size_t)(128 + t) * STATS_BLOCKS + blockIdx.x] = tot;
    }
}

// ---------------- reduce partials + fold BN params ----------------
// one block per column; rows of `partials` are contiguous -> coalesced
__global__ __launch_bounds__(256) void bn_reduce_params_k(const float* __restrict__ partials,
    const float* __restrict__ gamma, const float* __restrict__ beta,
    float* __restrict__ ab, float n)
{
    const int c = blockIdx.x;      // 0..127
    const int t = threadIdx.x;     // 256
    float s = 0.f, q = 0.f;
    for (int b = t; b < STATS_BLOCKS; b += 256) {
        s += partials[(size_t)c * STATS_BLOCKS + b];
        q += partials[(size_t)(128 + c) * STATS_BLOCKS + b];
    }
#pragma unroll
    for (int off = 32; off > 0; off >>= 1) {
        s += __shfl_xor(s, off);
        q += __shfl_xor(q, off);
    }
    __shared__ float ss[4], qq[4];
    const int lane = t & 63, w = t >> 6;
    if (lane == 0) { ss[w] = s; qq[w] = q; }
    __syncthreads();
    if (t == 0) {
        float S = ss[0] + ss[1] + ss[2] + ss[3];
        float Q = qq[0] + qq[1] + qq[2] + qq[3];
        float mean = S / n;
        float var = Q / n - mean * mean;
        float a = rsqrtf(var + 1e-5f) * gamma[c];
        ab[c] = a;
        ab[c + 128] = beta[c] - mean * a;
    }
}

// ---------------- BN apply ----------------
__global__ __launch_bounds__(256) void bn_apply_k(float* __restrict__ h,
    const float* __restrict__ ab, int total4)
{
    int i4 = blockIdx.x * blockDim.x + threadIdx.x;
    if (i4 >= total4) return;
    int cg = i4 & 31;
    float4 v = ((const float4*)h)[i4];
    float4 a = ((const float4*)ab)[cg];
    float4 b = ((const float4*)(ab + 128))[cg];
    ((float4*)h)[i4] = make_float4(v.x * a.x + b.x, v.y * a.y + b.y,
                                   v.z * a.z + b.z, v.w * a.w + b.w);
}

extern "C" void kernel_launch(void* const* d_in, const int* in_sizes, int n_in,
                              void* d_out, int out_size, void* d_ws, size_t ws_size,
                              hipStream_t stream)
{
    const float* x    = (const float*)d_in[0];
    const int*   ei   = (const int*)d_in[1];
    const float* ea   = (const float*)d_in[2];
    const float* Wl   = (const float*)d_in[3];
    const float* bl   = (const float*)d_in[4];
    const float* Wr   = (const float*)d_in[5];
    const float* br   = (const float*)d_in[6];
    const float* We   = (const float*)d_in[7];
    const float* att  = (const float*)d_in[8];
    const float* bias = (const float*)d_in[9];
    const float* gamma= (const float*)d_in[10];
    const float* beta = (const float*)d_in[11];
    float* out = (float*)d_out;

    const int n = in_sizes[0] / D;
    const int E = in_sizes[1] / 2;

    float* ws = (float*)d_ws;
    float* xl = ws;                                   // n*D
    float* xr = xl + (size_t)n * D;                   // n*D
    int* deg = (int*)(xr + (size_t)n * D);            // n   (becomes cursor)
    int* rowptr = deg + n;                            // n+1
    int* srcs = rowptr + n + 1;                       // E
    float* eas = (float*)(srcs + E);                  // E
    float* partials = eas + E;                        // 256*STATS_BLOCKS
    float* ab = partials + 256 * STATS_BLOCKS;        // 256

    hipMemsetAsync(deg, 0, (size_t)n * 4, stream);

    dim3 gg((n + 31) / 32, 2);
    gemm_k<<<gg, 256, 0, stream>>>(x, Wl, bl, Wr, br, xl, xr, n);
    hist_k<<<(E + 255) / 256, 256, 0, stream>>>(ei, deg, E);
    scan_k<<<1, 1024, 0, stream>>>(deg, rowptr, n);
    scatter_k<<<(E + 255) / 256, 256, 0, stream>>>(ei, ea, deg, srcs, eas, E);
    agg_k<<<(n + 3) / 4, 256, 0, stream>>>(xl, xr, rowptr, srcs, eas, We, att, out, n);
    const int total4 = (n * D) / 4;
    gelu_stats_k<<<STATS_BLOCKS, 256, 0, stream>>>(x, bias, out, partials, total4);
    bn_reduce_params_k<<<128, 256, 0, stream>>>(partials, gamma, beta, ab, (float)n);
    bn_apply_k<<<(total4 + 255) / 256, 256, 0, stream>>>(out, ab, total4);
}

// Round 4
// 266.965 us; speedup vs baseline: 3.5353x; 1.3851x over previous
//
#include <hip/hip_runtime.h>
#include <math.h>

#define D 128
#define STATS_BLOCKS 512
#define SCAN_CHUNK 256

// ---------------- GEMM: xl = x@Wl+bl, xr = x@Wr+br ----------------
__global__ __launch_bounds__(256) void gemm_k(const float* __restrict__ x,
    const float* __restrict__ Wl, const float* __restrict__ bl,
    const float* __restrict__ Wr, const float* __restrict__ br,
    float* __restrict__ xl, float* __restrict__ xr, int n)
{
    __shared__ float Ws[128 * 128];   // W[k][c], 64KB
    __shared__ float xs[32 * 128];    // 16KB
    const int t = threadIdx.x;
    const float* W   = blockIdx.y ? Wr : Wl;
    const float* bia = blockIdx.y ? br : bl;
    float* out       = blockIdx.y ? xr : xl;

    const float4* W4 = (const float4*)W;
    float4* Ws4 = (float4*)Ws;
#pragma unroll
    for (int i = 0; i < 16; i++) Ws4[t + 256 * i] = W4[t + 256 * i];

    const int row0 = blockIdx.x * 32;
    const int avail = n - row0;
    const float4* x4 = (const float4*)(x + (size_t)row0 * D);
    float4* xs4 = (float4*)xs;
#pragma unroll
    for (int i = 0; i < 4; i++) {
        int idx = t + 256 * i;
        if ((idx >> 5) < avail) xs4[idx] = x4[idx];
        else xs4[idx] = make_float4(0.f, 0.f, 0.f, 0.f);
    }
    __syncthreads();

    const int tc = (t & 31) * 4;
    const int tr = (t >> 5) * 4;
    float acc[4][4];
#pragma unroll
    for (int i = 0; i < 4; i++)
#pragma unroll
        for (int j = 0; j < 4; j++) acc[i][j] = 0.f;

    for (int k = 0; k < 128; k += 4) {
        float4 xv[4];
#pragma unroll
        for (int i = 0; i < 4; i++) xv[i] = *(const float4*)&xs[(tr + i) * 128 + k];
#pragma unroll
        for (int kk = 0; kk < 4; kk++) {
            float4 wv = *(const float4*)&Ws[(k + kk) * 128 + tc];
#pragma unroll
            for (int i = 0; i < 4; i++) {
                float xvk = kk == 0 ? xv[i].x : kk == 1 ? xv[i].y : kk == 2 ? xv[i].z : xv[i].w;
                acc[i][0] += xvk * wv.x;
                acc[i][1] += xvk * wv.y;
                acc[i][2] += xvk * wv.z;
                acc[i][3] += xvk * wv.w;
            }
        }
    }

    float4 bv = *(const float4*)&bia[tc];
#pragma unroll
    for (int i = 0; i < 4; i++) {
        int row = row0 + tr + i;
        if (row < n) {
            float4 o = make_float4(acc[i][0] + bv.x, acc[i][1] + bv.y,
                                   acc[i][2] + bv.z, acc[i][3] + bv.w);
            *(float4*)&out[(size_t)row * D + tc] = o;
        }
    }
}

// ---------------- CSR build: histogram ----------------
__global__ __launch_bounds__(256) void hist_k(const int* __restrict__ ei,
    int* __restrict__ deg, int E)
{
    int e = blockIdx.x * blockDim.x + threadIdx.x;
    if (e < E) atomicAdd(&deg[ei[E + e]], 1);
}

// ---------------- hierarchical scan, stage 1: per-block chunk sums ----------------
__global__ __launch_bounds__(256) void scan_sum_k(const int* __restrict__ deg,
    int* __restrict__ bsum, int n)
{
    const int t = threadIdx.x;
    const int i = blockIdx.x * SCAN_CHUNK + t;
    int s = (i < n) ? deg[i] : 0;
#pragma unroll
    for (int off = 32; off > 0; off >>= 1) s += __shfl_xor(s, off);
    __shared__ int ws_[4];
    const int lane = t & 63, w = t >> 6;
    if (lane == 0) ws_[w] = s;
    __syncthreads();
    if (t == 0) bsum[blockIdx.x] = ws_[0] + ws_[1] + ws_[2] + ws_[3];
}

// ---------------- stage 2: exclusive scan of block sums (nb <= 256) ----------------
__global__ __launch_bounds__(256) void scan_off_k(const int* __restrict__ bsum,
    int* __restrict__ boff, int* __restrict__ rowptr, int nb, int n)
{
    const int t = threadIdx.x;
    int v = (t < nb) ? bsum[t] : 0;
    const int lane = t & 63, w = t >> 6;
    int inc = v;
#pragma unroll
    for (int off = 1; off < 64; off <<= 1) {
        int u = __shfl_up(inc, off);
        if (lane >= off) inc += u;
    }
    __shared__ int wsum[4], wpre[4];
    if (lane == 63) wsum[w] = inc;
    __syncthreads();
    if (t == 0) {
        int r = 0;
#pragma unroll
        for (int j = 0; j < 4; j++) { wpre[j] = r; r += wsum[j]; }
        rowptr[n] = r;
    }
    __syncthreads();
    if (t < nb) boff[t] = inc - v + wpre[w];
}

// ---------------- stage 3: in-block exclusive scan + offset ----------------
__global__ __launch_bounds__(256) void scan_fin_k(int* __restrict__ deg,
    const int* __restrict__ boff, int* __restrict__ rowptr, int n)
{
    const int t = threadIdx.x;
    const int i = blockIdx.x * SCAN_CHUNK + t;
    int v = (i < n) ? deg[i] : 0;
    const int lane = t & 63, w = t >> 6;
    int inc = v;
#pragma unroll
    for (int off = 1; off < 64; off <<= 1) {
        int u = __shfl_up(inc, off);
        if (lane >= off) inc += u;
    }
    __shared__ int wsum[4], wpre[4];
    if (lane == 63) wsum[w] = inc;
    __syncthreads();
    if (t == 0) {
        int r = 0;
#pragma unroll
        for (int j = 0; j < 4; j++) { wpre[j] = r; r += wsum[j]; }
    }
    __syncthreads();
    if (i < n) {
        int ex = inc - v + wpre[w] + boff[blockIdx.x];
        rowptr[i] = ex;
        deg[i] = ex;                 // scatter cursor
    }
}

// ---------------- CSR build: scatter edges into dst-grouped order ----------------
__global__ __launch_bounds__(256) void scatter_k(const int* __restrict__ ei,
    const float* __restrict__ ea, int* __restrict__ cursor,
    int* __restrict__ srcs, float* __restrict__ eas, int E)
{
    int e = blockIdx.x * blockDim.x + threadIdx.x;
    if (e >= E) return;
    int dst = ei[E + e];
    int pos = atomicAdd(&cursor[dst], 1);
    srcs[pos] = ei[e];
    eas[pos] = ea[e];
}

// ---------------- fused edge logits + online softmax + aggregate ----------------
// one 64-lane wave per destination node; lane owns 2 feature columns
__global__ __launch_bounds__(256) void agg_k(const float* __restrict__ xl,
    const float* __restrict__ xr, const int* __restrict__ rowptr,
    const int* __restrict__ srcs, const float* __restrict__ eas,
    const float* __restrict__ We, const float* __restrict__ att,
    float* __restrict__ out, int n)
{
    int wave = threadIdx.x >> 6;
    int lane = threadIdx.x & 63;
    int v = blockIdx.x * 4 + wave;
    if (v >= n) return;
    int beg = rowptr[v];
    int end = rowptr[v + 1];
    int c = lane * 2;
    float2 xrv = *(const float2*)(xr + (size_t)v * D + c);
    float2 wev = *(const float2*)(We + c);
    float2 atv = *(const float2*)(att + c);

    float m = -INFINITY, s = 0.f, acc0 = 0.f, acc1 = 0.f;
    for (int j = beg; j < end; j++) {
        int src = srcs[j];
        float eav = eas[j];
        float2 xv = *(const float2*)(xl + (size_t)src * D + c);
        float m0 = xv.x + xrv.x + eav * wev.x;
        float m1 = xv.y + xrv.y + eav * wev.y;
        m0 = m0 > 0.f ? m0 : 0.2f * m0;
        m1 = m1 > 0.f ? m1 : 0.2f * m1;
        float p = m0 * atv.x + m1 * atv.y;
#pragma unroll
        for (int off = 32; off > 0; off >>= 1) p += __shfl_xor(p, off);
        float mn = fmaxf(m, p);
        float sc = __expf(m - mn);   // first iter: exp(-inf)=0
        float w  = __expf(p - mn);
        s = s * sc + w;
        acc0 = acc0 * sc + w * xv.x;
        acc1 = acc1 * sc + w * xv.y;
        m = mn;
    }
    float inv = 1.f / (s + 1e-16f);   // deg==0 -> acc=0 -> out=0
    *(float2*)(out + (size_t)v * D + c) = make_float2(acc0 * inv, acc1 * inv);
}

// ---------------- residual + GELU(erf) + BN stats (atomic-free) ----------------
__global__ __launch_bounds__(256) void gelu_stats_k(const float* __restrict__ x,
    const float* __restrict__ bias, float* __restrict__ h,
    float* __restrict__ partials, int total4)
{
    const int t = threadIdx.x;
    const int c0 = (t & 31) * 4;
    const float4 bv = *(const float4*)&bias[c0];
    float sum[4] = {0.f, 0.f, 0.f, 0.f}, sq[4] = {0.f, 0.f, 0.f, 0.f};
    const int stride = gridDim.x * blockDim.x;
    for (int i4 = blockIdx.x * blockDim.x + t; i4 < total4; i4 += stride) {
        float4 g4 = ((const float4*)h)[i4];
        float4 xv = ((const float4*)x)[i4];
        float hv[4] = {xv.x + g4.x + bv.x, xv.y + g4.y + bv.y,
                       xv.z + g4.z + bv.z, xv.w + g4.w + bv.w};
        float res[4];
#pragma unroll
        for (int j = 0; j < 4; j++) {
            float ge = 0.5f * hv[j] * (1.f + erff(hv[j] * 0.70710678118654752f));
            res[j] = ge;
            sum[j] += ge;
            sq[j] += ge * ge;
        }
        ((float4*)h)[i4] = make_float4(res[0], res[1], res[2], res[3]);
    }
    __shared__ float red[8][128];
    const int slot = t >> 5;
#pragma unroll
    for (int j = 0; j < 4; j++) red[slot][c0 + j] = sum[j];
    __syncthreads();
    if (t < 128) {
        float tot = 0.f;
#pragma unroll
        for (int s2 = 0; s2 < 8; s2++) tot += red[s2][t];
        partials[(size_t)t * STATS_BLOCKS + blockIdx.x] = tot;
    }
    __syncthreads();
#pragma unroll
    for (int j = 0; j < 4; j++) red[slot][c0 + j] = sq[j];
    __syncthreads();
    if (t < 128) {
        float tot = 0.f;
#pragma unroll
        for (int s2 = 0; s2 < 8; s2++) tot += red[s2][t];
        partials[(size_t)(128 + t) * STATS_BLOCKS + blockIdx.x] = tot;
    }
}

// ---------------- reduce partials + fold BN params ----------------
__global__ __launch_bounds__(256) void bn_reduce_params_k(const float* __restrict__ partials,
    const float* __restrict__ gamma, const float* __restrict__ beta,
    float* __restrict__ ab, float n)
{
    const int c = blockIdx.x;      // 0..127
    const int t = threadIdx.x;     // 256
    float s = 0.f, q = 0.f;
    for (int b = t; b < STATS_BLOCKS; b += 256) {
        s += partials[(size_t)c * STATS_BLOCKS + b];
        q += partials[(size_t)(128 + c) * STATS_BLOCKS + b];
    }
#pragma unroll
    for (int off = 32; off > 0; off >>= 1) {
        s += __shfl_xor(s, off);
        q += __shfl_xor(q, off);
    }
    __shared__ float ss[4], qq[4];
    const int lane = t & 63, w = t >> 6;
    if (lane == 0) { ss[w] = s; qq[w] = q; }
    __syncthreads();
    if (t == 0) {
        float S = ss[0] + ss[1] + ss[2] + ss[3];
        float Q = qq[0] + qq[1] + qq[2] + qq[3];
        float mean = S / n;
        float var = Q / n - mean * mean;
        float a = rsqrtf(var + 1e-5f) * gamma[c];
        ab[c] = a;
        ab[c + 128] = beta[c] - mean * a;
    }
}

// ---------------- BN apply ----------------
__global__ __launch_bounds__(256) void bn_apply_k(float* __restrict__ h,
    const float* __restrict__ ab, int total4)
{
    int i4 = blockIdx.x * blockDim.x + threadIdx.x;
    if (i4 >= total4) return;
    int cg = i4 & 31;
    float4 v = ((const float4*)h)[i4];
    float4 a = ((const float4*)ab)[cg];
    float4 b = ((const float4*)(ab + 128))[cg];
    ((float4*)h)[i4] = make_float4(v.x * a.x + b.x, v.y * a.y + b.y,
                                   v.z * a.z + b.z, v.w * a.w + b.w);
}

extern "C" void kernel_launch(void* const* d_in, const int* in_sizes, int n_in,
                              void* d_out, int out_size, void* d_ws, size_t ws_size,
                              hipStream_t stream)
{
    const float* x    = (const float*)d_in[0];
    const int*   ei   = (const int*)d_in[1];
    const float* ea   = (const float*)d_in[2];
    const float* Wl   = (const float*)d_in[3];
    const float* bl   = (const float*)d_in[4];
    const float* Wr   = (const float*)d_in[5];
    const float* br   = (const float*)d_in[6];
    const float* We   = (const float*)d_in[7];
    const float* att  = (const float*)d_in[8];
    const float* bias = (const float*)d_in[9];
    const float* gamma= (const float*)d_in[10];
    const float* beta = (const float*)d_in[11];
    float* out = (float*)d_out;

    const int n = in_sizes[0] / D;
    const int E = in_sizes[1] / 2;
    const int nb = (n + SCAN_CHUNK - 1) / SCAN_CHUNK;   // 196 for n=50000

    float* ws = (float*)d_ws;
    float* xl = ws;                                   // n*D
    float* xr = xl + (size_t)n * D;                   // n*D
    int* deg = (int*)(xr + (size_t)n * D);            // n   (becomes cursor)
    int* rowptr = deg + n;                            // n+1
    int* srcs = rowptr + n + 1;                       // E
    float* eas = (float*)(srcs + E);                  // E
    float* partials = eas + E;                        // 256*STATS_BLOCKS
    int* bsum = (int*)(partials + 256 * STATS_BLOCKS);// nb
    int* boff = bsum + nb;                            // nb
    float* ab = (float*)(boff + nb);                  // 256

    hipMemsetAsync(deg, 0, (size_t)n * 4, stream);

    dim3 gg((n + 31) / 32, 2);
    gemm_k<<<gg, 256, 0, stream>>>(x, Wl, bl, Wr, br, xl, xr, n);
    hist_k<<<(E + 255) / 256, 256, 0, stream>>>(ei, deg, E);
    scan_sum_k<<<nb, 256, 0, stream>>>(deg, bsum, n);
    scan_off_k<<<1, 256, 0, stream>>>(bsum, boff, rowptr, nb, n);
    scan_fin_k<<<nb, 256, 0, stream>>>(deg, boff, rowptr, n);
    scatter_k<<<(E + 255) / 256, 256, 0, stream>>>(ei, ea, deg, srcs, eas, E);
    agg_k<<<(n + 3) / 4, 256, 0, stream>>>(xl, xr, rowptr, srcs, eas, We, att, out, n);
    const int total4 = (n * D) / 4;
    gelu_stats_k<<<STATS_BLOCKS, 256, 0, stream>>>(x, bias, out, partials, total4);
    bn_reduce_params_k<<<128, 256, 0, stream>>>(partials, gamma, beta, ab, (float)n);
    bn_apply_k<<<(total4 + 255) / 256, 256, 0, stream>>>(out, ab, total4);
}

// Round 5
// 236.440 us; speedup vs baseline: 3.9917x; 1.1291x over previous
//
#include <hip/hip_runtime.h>
#include <math.h>

#define D 128
#define STATS_BLOCKS 512
#define SCAN_CHUNK 256

__device__ __forceinline__ unsigned short f2bf(float f) {
    unsigned u = __float_as_uint(f);
    unsigned r = (u + 0x7fff + ((u >> 16) & 1)) >> 16;   // RNE
    return (unsigned short)r;
}

// ---------------- GEMM: xl(bf16) = x@Wl+bl, xr(f32) = x@Wr+br ----------------
__global__ __launch_bounds__(256) void gemm_k(const float* __restrict__ x,
    const float* __restrict__ Wl, const float* __restrict__ bl,
    const float* __restrict__ Wr, const float* __restrict__ br,
    unsigned* __restrict__ xlb, float* __restrict__ xr, int n)
{
    __shared__ float Ws[128 * 128];   // W[k][c], 64KB
    __shared__ float xs[32 * 128];    // 16KB
    const int t = threadIdx.x;
    const float* W   = blockIdx.y ? Wr : Wl;
    const float* bia = blockIdx.y ? br : bl;

    const float4* W4 = (const float4*)W;
    float4* Ws4 = (float4*)Ws;
#pragma unroll
    for (int i = 0; i < 16; i++) Ws4[t + 256 * i] = W4[t + 256 * i];

    const int row0 = blockIdx.x * 32;
    const int avail = n - row0;
    const float4* x4 = (const float4*)(x + (size_t)row0 * D);
    float4* xs4 = (float4*)xs;
#pragma unroll
    for (int i = 0; i < 4; i++) {
        int idx = t + 256 * i;
        if ((idx >> 5) < avail) xs4[idx] = x4[idx];
        else xs4[idx] = make_float4(0.f, 0.f, 0.f, 0.f);
    }
    __syncthreads();

    const int tc = (t & 31) * 4;
    const int tr = (t >> 5) * 4;
    float acc[4][4];
#pragma unroll
    for (int i = 0; i < 4; i++)
#pragma unroll
        for (int j = 0; j < 4; j++) acc[i][j] = 0.f;

    for (int k = 0; k < 128; k += 4) {
        float4 xv[4];
#pragma unroll
        for (int i = 0; i < 4; i++) xv[i] = *(const float4*)&xs[(tr + i) * 128 + k];
#pragma unroll
        for (int kk = 0; kk < 4; kk++) {
            float4 wv = *(const float4*)&Ws[(k + kk) * 128 + tc];
#pragma unroll
            for (int i = 0; i < 4; i++) {
                float xvk = kk == 0 ? xv[i].x : kk == 1 ? xv[i].y : kk == 2 ? xv[i].z : xv[i].w;
                acc[i][0] += xvk * wv.x;
                acc[i][1] += xvk * wv.y;
                acc[i][2] += xvk * wv.z;
                acc[i][3] += xvk * wv.w;
            }
        }
    }

    float4 bv = *(const float4*)&bia[tc];
#pragma unroll
    for (int i = 0; i < 4; i++) {
        int row = row0 + tr + i;
        if (row < n) {
            float o0 = acc[i][0] + bv.x, o1 = acc[i][1] + bv.y;
            float o2 = acc[i][2] + bv.z, o3 = acc[i][3] + bv.w;
            if (blockIdx.y == 0) {
                unsigned p0 = (unsigned)f2bf(o0) | ((unsigned)f2bf(o1) << 16);
                unsigned p1 = (unsigned)f2bf(o2) | ((unsigned)f2bf(o3) << 16);
                *(uint2*)&xlb[(size_t)row * 64 + (tc >> 1)] = make_uint2(p0, p1);
            } else {
                *(float4*)&xr[(size_t)row * D + tc] = make_float4(o0, o1, o2, o3);
            }
        }
    }
}

// ---------------- CSR build: histogram ----------------
__global__ __launch_bounds__(256) void hist_k(const int* __restrict__ ei,
    int* __restrict__ deg, int E)
{
    int e = blockIdx.x * blockDim.x + threadIdx.x;
    if (e < E) atomicAdd(&deg[ei[E + e]], 1);
}

// ---------------- hierarchical scan, stage 1: per-block chunk sums ----------------
__global__ __launch_bounds__(256) void scan_sum_k(const int* __restrict__ deg,
    int* __restrict__ bsum, int n)
{
    const int t = threadIdx.x;
    const int i = blockIdx.x * SCAN_CHUNK + t;
    int s = (i < n) ? deg[i] : 0;
#pragma unroll
    for (int off = 32; off > 0; off >>= 1) s += __shfl_xor(s, off);
    __shared__ int ws_[4];
    const int lane = t & 63, w = t >> 6;
    if (lane == 0) ws_[w] = s;
    __syncthreads();
    if (t == 0) bsum[blockIdx.x] = ws_[0] + ws_[1] + ws_[2] + ws_[3];
}

// ---------------- stage 2: exclusive scan of block sums (nb <= 256) ----------------
__global__ __launch_bounds__(256) void scan_off_k(const int* __restrict__ bsum,
    int* __restrict__ boff, int* __restrict__ rowptr, int nb, int n)
{
    const int t = threadIdx.x;
    int v = (t < nb) ? bsum[t] : 0;
    const int lane = t & 63, w = t >> 6;
    int inc = v;
#pragma unroll
    for (int off = 1; off < 64; off <<= 1) {
        int u = __shfl_up(inc, off);
        if (lane >= off) inc += u;
    }
    __shared__ int wsum[4], wpre[4];
    if (lane == 63) wsum[w] = inc;
    __syncthreads();
    if (t == 0) {
        int r = 0;
#pragma unroll
        for (int j = 0; j < 4; j++) { wpre[j] = r; r += wsum[j]; }
        rowptr[n] = r;
    }
    __syncthreads();
    if (t < nb) boff[t] = inc - v + wpre[w];
}

// ---------------- stage 3: in-block exclusive scan + offset ----------------
__global__ __launch_bounds__(256) void scan_fin_k(int* __restrict__ deg,
    const int* __restrict__ boff, int* __restrict__ rowptr, int n)
{
    const int t = threadIdx.x;
    const int i = blockIdx.x * SCAN_CHUNK + t;
    int v = (i < n) ? deg[i] : 0;
    const int lane = t & 63, w = t >> 6;
    int inc = v;
#pragma unroll
    for (int off = 1; off < 64; off <<= 1) {
        int u = __shfl_up(inc, off);
        if (lane >= off) inc += u;
    }
    __shared__ int wsum[4], wpre[4];
    if (lane == 63) wsum[w] = inc;
    __syncthreads();
    if (t == 0) {
        int r = 0;
#pragma unroll
        for (int j = 0; j < 4; j++) { wpre[j] = r; r += wsum[j]; }
    }
    __syncthreads();
    if (i < n) {
        int ex = inc - v + wpre[w] + boff[blockIdx.x];
        rowptr[i] = ex;
        deg[i] = ex;                 // scatter cursor
    }
}

// ---------------- CSR build: scatter {src, ea} pairs into dst-grouped order ----------------
__global__ __launch_bounds__(256) void scatter_k(const int* __restrict__ ei,
    const float* __restrict__ ea, int* __restrict__ cursor,
    uint2* __restrict__ edges, int E)
{
    int e = blockIdx.x * blockDim.x + threadIdx.x;
    if (e >= E) return;
    int dst = ei[E + e];
    int pos = atomicAdd(&cursor[dst], 1);
    edges[pos] = make_uint2((unsigned)ei[e], __float_as_uint(ea[e]));
}

// ---------------- fused edge logits + online softmax + aggregate ----------------
// one 64-lane wave per destination node; lane owns 2 feature columns;
// bf16 xl gather, prefetch pipeline, single-exp deferred-rescale update
__global__ __launch_bounds__(256) void agg_k(const unsigned* __restrict__ xlb,
    const float* __restrict__ xr, const int* __restrict__ rowptr,
    const uint2* __restrict__ edges, const float* __restrict__ We,
    const float* __restrict__ att, float* __restrict__ out, int n)
{
    int wave = threadIdx.x >> 6;
    int lane = threadIdx.x & 63;
    int v = blockIdx.x * 4 + wave;
    if (v >= n) return;
    int beg = rowptr[v];
    int end = rowptr[v + 1];
    int c = lane * 2;
    float2 xrv = *(const float2*)(xr + (size_t)v * D + c);
    float2 wev = *(const float2*)(We + c);
    float2 atv = *(const float2*)(att + c);

    float m = -INFINITY, s = 0.f, acc0 = 0.f, acc1 = 0.f;
    uint2 e2 = make_uint2(0u, 0u);
    unsigned xb = 0u;
    if (beg < end) {
        e2 = edges[beg];
        xb = xlb[(size_t)e2.x * 64 + lane];
    }
    for (int j = beg; j < end; j++) {
        // prefetch next edge (clamped; redundant reload on last iter)
        int jn = (j + 1 < end) ? j + 1 : j;
        uint2 e2n = edges[jn];
        unsigned xbn = xlb[(size_t)e2n.x * 64 + lane];

        float eav = __uint_as_float(e2.y);
        float xv0 = __uint_as_float(xb << 16);
        float xv1 = __uint_as_float(xb & 0xffff0000u);
        float m0 = xv0 + xrv.x + eav * wev.x;
        float m1 = xv1 + xrv.y + eav * wev.y;
        m0 = m0 > 0.f ? m0 : 0.2f * m0;
        m1 = m1 > 0.f ? m1 : 0.2f * m1;
        float p = m0 * atv.x + m1 * atv.y;
#pragma unroll
        for (int off = 32; off > 0; off >>= 1) p += __shfl_xor(p, off);
        // p identical on all 64 lanes; m,s identical -> branch is wave-uniform
        if (p > m) {
            float sc = __expf(m - p);    // first iter: exp(-inf)=0
            s = s * sc + 1.f;
            acc0 = acc0 * sc + xv0;
            acc1 = acc1 * sc + xv1;
            m = p;
        } else {
            float w = __expf(p - m);
            s += w;
            acc0 += w * xv0;
            acc1 += w * xv1;
        }
        e2 = e2n;
        xb = xbn;
    }
    float inv = 1.f / (s + 1e-16f);   // deg==0 -> acc=0 -> out=0
    *(float2*)(out + (size_t)v * D + c) = make_float2(acc0 * inv, acc1 * inv);
}

// ---------------- residual + GELU(erf) + BN stats (atomic-free) ----------------
__global__ __launch_bounds__(256) void gelu_stats_k(const float* __restrict__ x,
    const float* __restrict__ bias, float* __restrict__ h,
    float* __restrict__ partials, int total4)
{
    const int t = threadIdx.x;
    const int c0 = (t & 31) * 4;
    const float4 bv = *(const float4*)&bias[c0];
    float sum[4] = {0.f, 0.f, 0.f, 0.f}, sq[4] = {0.f, 0.f, 0.f, 0.f};
    const int stride = gridDim.x * blockDim.x;
    for (int i4 = blockIdx.x * blockDim.x + t; i4 < total4; i4 += stride) {
        float4 g4 = ((const float4*)h)[i4];
        float4 xv = ((const float4*)x)[i4];
        float hv[4] = {xv.x + g4.x + bv.x, xv.y + g4.y + bv.y,
                       xv.z + g4.z + bv.z, xv.w + g4.w + bv.w};
        float res[4];
#pragma unroll
        for (int j = 0; j < 4; j++) {
            float ge = 0.5f * hv[j] * (1.f + erff(hv[j] * 0.70710678118654752f));
            res[j] = ge;
            sum[j] += ge;
            sq[j] += ge * ge;
        }
        ((float4*)h)[i4] = make_float4(res[0], res[1], res[2], res[3]);
    }
    __shared__ float red[8][128];
    const int slot = t >> 5;
#pragma unroll
    for (int j = 0; j < 4; j++) red[slot][c0 + j] = sum[j];
    __syncthreads();
    if (t < 128) {
        float tot = 0.f;
#pragma unroll
        for (int s2 = 0; s2 < 8; s2++) tot += red[s2][t];
        partials[(size_t)t * STATS_BLOCKS + blockIdx.x] = tot;
    }
    __syncthreads();
#pragma unroll
    for (int j = 0; j < 4; j++) red[slot][c0 + j] = sq[j];
    __syncthreads();
    if (t < 128) {
        float tot = 0.f;
#pragma unroll
        for (int s2 = 0; s2 < 8; s2++) tot += red[s2][t];
        partials[(size_t)(128 + t) * STATS_BLOCKS + blockIdx.x] = tot;
    }
}

// ---------------- reduce partials + fold BN params ----------------
__global__ __launch_bounds__(256) void bn_reduce_params_k(const float* __restrict__ partials,
    const float* __restrict__ gamma, const float* __restrict__ beta,
    float* __restrict__ ab, float n)
{
    const int c = blockIdx.x;      // 0..127
    const int t = threadIdx.x;     // 256
    float s = 0.f, q = 0.f;
    for (int b = t; b < STATS_BLOCKS; b += 256) {
        s += partials[(size_t)c * STATS_BLOCKS + b];
        q += partials[(size_t)(128 + c) * STATS_BLOCKS + b];
    }
#pragma unroll
    for (int off = 32; off > 0; off >>= 1) {
        s += __shfl_xor(s, off);
        q += __shfl_xor(q, off);
    }
    __shared__ float ss[4], qq[4];
    const int lane = t & 63, w = t >> 6;
    if (lane == 0) { ss[w] = s; qq[w] = q; }
    __syncthreads();
    if (t == 0) {
        float S = ss[0] + ss[1] + ss[2] + ss[3];
        float Q = qq[0] + qq[1] + qq[2] + qq[3];
        float mean = S / n;
        float var = Q / n - mean * mean;
        float a = rsqrtf(var + 1e-5f) * gamma[c];
        ab[c] = a;
        ab[c + 128] = beta[c] - mean * a;
    }
}

// ---------------- BN apply ----------------
__global__ __launch_bounds__(256) void bn_apply_k(float* __restrict__ h,
    const float* __restrict__ ab, int total4)
{
    int i4 = blockIdx.x * blockDim.x + threadIdx.x;
    if (i4 >= total4) return;
    int cg = i4 & 31;
    float4 v = ((const float4*)h)[i4];
    float4 a = ((const float4*)ab)[cg];
    float4 b = ((const float4*)(ab + 128))[cg];
    ((float4*)h)[i4] = make_float4(v.x * a.x + b.x, v.y * a.y + b.y,
                                   v.z * a.z + b.z, v.w * a.w + b.w);
}

extern "C" void kernel_launch(void* const* d_in, const int* in_sizes, int n_in,
                              void* d_out, int out_size, void* d_ws, size_t ws_size,
                              hipStream_t stream)
{
    const float* x    = (const float*)d_in[0];
    const int*   ei   = (const int*)d_in[1];
    const float* ea   = (const float*)d_in[2];
    const float* Wl   = (const float*)d_in[3];
    const float* bl   = (const float*)d_in[4];
    const float* Wr   = (const float*)d_in[5];
    const float* br   = (const float*)d_in[6];
    const float* We   = (const float*)d_in[7];
    const float* att  = (const float*)d_in[8];
    const float* bias = (const float*)d_in[9];
    const float* gamma= (const float*)d_in[10];
    const float* beta = (const float*)d_in[11];
    float* out = (float*)d_out;

    const int n = in_sizes[0] / D;
    const int E = in_sizes[1] / 2;
    const int nb = (n + SCAN_CHUNK - 1) / SCAN_CHUNK;

    char* ws = (char*)d_ws;
    unsigned* xlb = (unsigned*)ws;                      // n*64 uints (bf16 xl)
    float* xr = (float*)(xlb + (size_t)n * 64);         // n*D floats
    int* deg = (int*)(xr + (size_t)n * D);              // n (becomes cursor)
    int* rowptr = deg + n;                              // n+1
    uintptr_t ep = ((uintptr_t)(rowptr + n + 1) + 7) & ~(uintptr_t)7;
    uint2* edges = (uint2*)ep;                          // E uint2
    float* partials = (float*)(edges + E);              // 256*STATS_BLOCKS
    int* bsum = (int*)(partials + 256 * STATS_BLOCKS);  // nb
    int* boff = bsum + nb;                              // nb
    float* ab = (float*)(boff + nb);                    // 256

    hipMemsetAsync(deg, 0, (size_t)n * 4, stream);

    dim3 gg((n + 31) / 32, 2);
    gemm_k<<<gg, 256, 0, stream>>>(x, Wl, bl, Wr, br, xlb, xr, n);
    hist_k<<<(E + 255) / 256, 256, 0, stream>>>(ei, deg, E);
    scan_sum_k<<<nb, 256, 0, stream>>>(deg, bsum, n);
    scan_off_k<<<1, 256, 0, stream>>>(bsum, boff, rowptr, nb, n);
    scan_fin_k<<<nb, 256, 0, stream>>>(deg, boff, rowptr, n);
    scatter_k<<<(E + 255) / 256, 256, 0, stream>>>(ei, ea, deg, edges, E);
    agg_k<<<(n + 3) / 4, 256, 0, stream>>>(xlb, xr, rowptr, edges, We, att, out, n);
    const int total4 = (n * D) / 4;
    gelu_stats_k<<<STATS_BLOCKS, 256, 0, stream>>>(x, bias, out, partials, total4);
    bn_reduce_params_k<<<128, 256, 0, stream>>>(partials, gamma, beta, ab, (float)n);
    bn_apply_k<<<(total4 + 255) / 256, 256, 0, stream>>>(out, ab, total4);
}

// Round 6
// 217.115 us; speedup vs baseline: 4.3470x; 1.0890x over previous
//
#include <hip/hip_runtime.h>
#include <math.h>

#define D 128
#define STATS_BLOCKS 512
#define SCAN_CHUNK 256

__device__ __forceinline__ unsigned short f2bf(float f) {
    unsigned u = __float_as_uint(f);
    unsigned r = (u + 0x7fff + ((u >> 16) & 1)) >> 16;   // RNE
    return (unsigned short)r;
}

// ---------------- GEMM: xl(bf16) = x@Wl+bl, xr(f32) = x@Wr+br ----------------
__global__ __launch_bounds__(256) void gemm_k(const float* __restrict__ x,
    const float* __restrict__ Wl, const float* __restrict__ bl,
    const float* __restrict__ Wr, const float* __restrict__ br,
    unsigned* __restrict__ xlb, float* __restrict__ xr, int n)
{
    __shared__ float Ws[128 * 128];   // W[k][c], 64KB
    __shared__ float xs[32 * 128];    // 16KB
    const int t = threadIdx.x;
    const float* W   = blockIdx.y ? Wr : Wl;
    const float* bia = blockIdx.y ? br : bl;

    const float4* W4 = (const float4*)W;
    float4* Ws4 = (float4*)Ws;
#pragma unroll
    for (int i = 0; i < 16; i++) Ws4[t + 256 * i] = W4[t + 256 * i];

    const int row0 = blockIdx.x * 32;
    const int avail = n - row0;
    const float4* x4 = (const float4*)(x + (size_t)row0 * D);
    float4* xs4 = (float4*)xs;
#pragma unroll
    for (int i = 0; i < 4; i++) {
        int idx = t + 256 * i;
        if ((idx >> 5) < avail) xs4[idx] = x4[idx];
        else xs4[idx] = make_float4(0.f, 0.f, 0.f, 0.f);
    }
    __syncthreads();

    const int tc = (t & 31) * 4;
    const int tr = (t >> 5) * 4;
    float acc[4][4];
#pragma unroll
    for (int i = 0; i < 4; i++)
#pragma unroll
        for (int j = 0; j < 4; j++) acc[i][j] = 0.f;

    for (int k = 0; k < 128; k += 4) {
        float4 xv[4];
#pragma unroll
        for (int i = 0; i < 4; i++) xv[i] = *(const float4*)&xs[(tr + i) * 128 + k];
#pragma unroll
        for (int kk = 0; kk < 4; kk++) {
            float4 wv = *(const float4*)&Ws[(k + kk) * 128 + tc];
#pragma unroll
            for (int i = 0; i < 4; i++) {
                float xvk = kk == 0 ? xv[i].x : kk == 1 ? xv[i].y : kk == 2 ? xv[i].z : xv[i].w;
                acc[i][0] += xvk * wv.x;
                acc[i][1] += xvk * wv.y;
                acc[i][2] += xvk * wv.z;
                acc[i][3] += xvk * wv.w;
            }
        }
    }

    float4 bv = *(const float4*)&bia[tc];
#pragma unroll
    for (int i = 0; i < 4; i++) {
        int row = row0 + tr + i;
        if (row < n) {
            float o0 = acc[i][0] + bv.x, o1 = acc[i][1] + bv.y;
            float o2 = acc[i][2] + bv.z, o3 = acc[i][3] + bv.w;
            if (blockIdx.y == 0) {
                unsigned p0 = (unsigned)f2bf(o0) | ((unsigned)f2bf(o1) << 16);
                unsigned p1 = (unsigned)f2bf(o2) | ((unsigned)f2bf(o3) << 16);
                *(uint2*)&xlb[(size_t)row * 64 + (tc >> 1)] = make_uint2(p0, p1);
            } else {
                *(float4*)&xr[(size_t)row * D + tc] = make_float4(o0, o1, o2, o3);
            }
        }
    }
}

// ---------------- CSR build: histogram ----------------
__global__ __launch_bounds__(256) void hist_k(const int* __restrict__ ei,
    int* __restrict__ deg, int E)
{
    int e = blockIdx.x * blockDim.x + threadIdx.x;
    if (e < E) atomicAdd(&deg[ei[E + e]], 1);
}

// ---------------- hierarchical scan, stage 1: per-block chunk sums ----------------
__global__ __launch_bounds__(256) void scan_sum_k(const int* __restrict__ deg,
    int* __restrict__ bsum, int n)
{
    const int t = threadIdx.x;
    const int i = blockIdx.x * SCAN_CHUNK + t;
    int s = (i < n) ? deg[i] : 0;
#pragma unroll
    for (int off = 32; off > 0; off >>= 1) s += __shfl_xor(s, off);
    __shared__ int ws_[4];
    const int lane = t & 63, w = t >> 6;
    if (lane == 0) ws_[w] = s;
    __syncthreads();
    if (t == 0) bsum[blockIdx.x] = ws_[0] + ws_[1] + ws_[2] + ws_[3];
}

// ---------------- stage 2: exclusive scan of block sums (nb <= 256) ----------------
__global__ __launch_bounds__(256) void scan_off_k(const int* __restrict__ bsum,
    int* __restrict__ boff, int* __restrict__ rowptr, int nb, int n)
{
    const int t = threadIdx.x;
    int v = (t < nb) ? bsum[t] : 0;
    const int lane = t & 63, w = t >> 6;
    int inc = v;
#pragma unroll
    for (int off = 1; off < 64; off <<= 1) {
        int u = __shfl_up(inc, off);
        if (lane >= off) inc += u;
    }
    __shared__ int wsum[4], wpre[4];
    if (lane == 63) wsum[w] = inc;
    __syncthreads();
    if (t == 0) {
        int r = 0;
#pragma unroll
        for (int j = 0; j < 4; j++) { wpre[j] = r; r += wsum[j]; }
        rowptr[n] = r;
    }
    __syncthreads();
    if (t < nb) boff[t] = inc - v + wpre[w];
}

// ---------------- stage 3: in-block exclusive scan + offset ----------------
__global__ __launch_bounds__(256) void scan_fin_k(int* __restrict__ deg,
    const int* __restrict__ boff, int* __restrict__ rowptr, int n)
{
    const int t = threadIdx.x;
    const int i = blockIdx.x * SCAN_CHUNK + t;
    int v = (i < n) ? deg[i] : 0;
    const int lane = t & 63, w = t >> 6;
    int inc = v;
#pragma unroll
    for (int off = 1; off < 64; off <<= 1) {
        int u = __shfl_up(inc, off);
        if (lane >= off) inc += u;
    }
    __shared__ int wsum[4], wpre[4];
    if (lane == 63) wsum[w] = inc;
    __syncthreads();
    if (t == 0) {
        int r = 0;
#pragma unroll
        for (int j = 0; j < 4; j++) { wpre[j] = r; r += wsum[j]; }
    }
    __syncthreads();
    if (i < n) {
        int ex = inc - v + wpre[w] + boff[blockIdx.x];
        rowptr[i] = ex;
        deg[i] = ex;                 // scatter cursor
    }
}

// ---------------- CSR build: scatter {src, ea} pairs into dst-grouped order ----------------
__global__ __launch_bounds__(256) void scatter_k(const int* __restrict__ ei,
    const float* __restrict__ ea, int* __restrict__ cursor,
    uint2* __restrict__ edges, int E)
{
    int e = blockIdx.x * blockDim.x + threadIdx.x;
    if (e >= E) return;
    int dst = ei[E + e];
    int pos = atomicAdd(&cursor[dst], 1);
    edges[pos] = make_uint2((unsigned)ei[e], __float_as_uint(ea[e]));
}

// ---------------- fused edge logits + online softmax + aggregate ----------------
// one 64-lane wave per destination node; lane owns 2 feature columns.
// 4 edges per iteration: independent shfl-reduce chains (4-way ILP),
// one group-max rescale, prefetch of the next group during compute.
__global__ __launch_bounds__(256) void agg_k(const unsigned* __restrict__ xlb,
    const float* __restrict__ xr, const int* __restrict__ rowptr,
    const uint2* __restrict__ edges, const float* __restrict__ We,
    const float* __restrict__ att, float* __restrict__ out, int n)
{
    int wave = threadIdx.x >> 6;
    int lane = threadIdx.x & 63;
    int v = blockIdx.x * 4 + wave;
    if (v >= n) return;
    int beg = rowptr[v];
    int end = rowptr[v + 1];
    int c = lane * 2;
    float2 xrv = *(const float2*)(xr + (size_t)v * D + c);
    float2 wev = *(const float2*)(We + c);
    float2 atv = *(const float2*)(att + c);

    float m = -INFINITY, s = 0.f, acc0 = 0.f, acc1 = 0.f;

    uint2 e2[4]; unsigned xb[4];
    if (beg < end) {
#pragma unroll
        for (int e = 0; e < 4; e++) {
            int jj = beg + e < end ? beg + e : end - 1;
            e2[e] = edges[jj];
            xb[e] = xlb[(size_t)e2[e].x * 64 + lane];
        }
    }
    for (int j = beg; j < end; j += 4) {
        // prefetch next group (clamped; redundant on last iter)
        int jn = j + 4;
        uint2 e2n[4]; unsigned xbn[4];
#pragma unroll
        for (int e = 0; e < 4; e++) {
            int jj = jn + e < end ? jn + e : end - 1;
            e2n[e] = edges[jj];
            xbn[e] = xlb[(size_t)e2n[e].x * 64 + lane];
        }

        float p[4], xv0[4], xv1[4];
#pragma unroll
        for (int e = 0; e < 4; e++) {
            float eav = __uint_as_float(e2[e].y);
            xv0[e] = __uint_as_float(xb[e] << 16);
            xv1[e] = __uint_as_float(xb[e] & 0xffff0000u);
            float m0 = xv0[e] + xrv.x + eav * wev.x;
            float m1 = xv1[e] + xrv.y + eav * wev.y;
            m0 = m0 > 0.f ? m0 : 0.2f * m0;
            m1 = m1 > 0.f ? m1 : 0.2f * m1;
            p[e] = m0 * atv.x + m1 * atv.y;
        }
        // 4 interleaved butterfly reductions (independent -> pipelined)
#pragma unroll
        for (int off = 32; off > 0; off >>= 1) {
#pragma unroll
            for (int e = 0; e < 4; e++) p[e] += __shfl_xor(p[e], off);
        }
        // mask tail edges
#pragma unroll
        for (int e = 1; e < 4; e++) if (j + e >= end) p[e] = -INFINITY;

        float pm = fmaxf(fmaxf(p[0], p[1]), fmaxf(p[2], p[3]));
        // wave-uniform branch: p[], m identical across lanes
        if (pm > m) {
            float sc = __expf(m - pm);   // first group: exp(-inf)=0
            s *= sc; acc0 *= sc; acc1 *= sc;
            m = pm;
        }
#pragma unroll
        for (int e = 0; e < 4; e++) {
            float w = __expf(p[e] - m);  // masked -> exp(-inf)=0
            s += w;
            acc0 += w * xv0[e];
            acc1 += w * xv1[e];
        }
#pragma unroll
        for (int e = 0; e < 4; e++) { e2[e] = e2n[e]; xb[e] = xbn[e]; }
    }
    float inv = 1.f / (s + 1e-16f);   // deg==0 -> acc=0 -> out=0
    *(float2*)(out + (size_t)v * D + c) = make_float2(acc0 * inv, acc1 * inv);
}

// ---------------- residual + GELU(erf) + BN stats (atomic-free) ----------------
__global__ __launch_bounds__(256) void gelu_stats_k(const float* __restrict__ x,
    const float* __restrict__ bias, float* __restrict__ h,
    float* __restrict__ partials, int total4)
{
    const int t = threadIdx.x;
    const int c0 = (t & 31) * 4;
    const float4 bv = *(const float4*)&bias[c0];
    float sum[4] = {0.f, 0.f, 0.f, 0.f}, sq[4] = {0.f, 0.f, 0.f, 0.f};
    const int stride = gridDim.x * blockDim.x;
    for (int i4 = blockIdx.x * blockDim.x + t; i4 < total4; i4 += stride) {
        float4 g4 = ((const float4*)h)[i4];
        float4 xv = ((const float4*)x)[i4];
        float hv[4] = {xv.x + g4.x + bv.x, xv.y + g4.y + bv.y,
                       xv.z + g4.z + bv.z, xv.w + g4.w + bv.w};
        float res[4];
#pragma unroll
        for (int j = 0; j < 4; j++) {
            float ge = 0.5f * hv[j] * (1.f + erff(hv[j] * 0.70710678118654752f));
            res[j] = ge;
            sum[j] += ge;
            sq[j] += ge * ge;
        }
        ((float4*)h)[i4] = make_float4(res[0], res[1], res[2], res[3]);
    }
    __shared__ float red[8][128];
    const int slot = t >> 5;
#pragma unroll
    for (int j = 0; j < 4; j++) red[slot][c0 + j] = sum[j];
    __syncthreads();
    if (t < 128) {
        float tot = 0.f;
#pragma unroll
        for (int s2 = 0; s2 < 8; s2++) tot += red[s2][t];
        partials[(size_t)t * STATS_BLOCKS + blockIdx.x] = tot;
    }
    __syncthreads();
#pragma unroll
    for (int j = 0; j < 4; j++) red[slot][c0 + j] = sq[j];
    __syncthreads();
    if (t < 128) {
        float tot = 0.f;
#pragma unroll
        for (int s2 = 0; s2 < 8; s2++) tot += red[s2][t];
        partials[(size_t)(128 + t) * STATS_BLOCKS + blockIdx.x] = tot;
    }
}

// ---------------- reduce partials + fold BN params ----------------
__global__ __launch_bounds__(256) void bn_reduce_params_k(const float* __restrict__ partials,
    const float* __restrict__ gamma, const float* __restrict__ beta,
    float* __restrict__ ab, float n)
{
    const int c = blockIdx.x;      // 0..127
    const int t = threadIdx.x;     // 256
    float s = 0.f, q = 0.f;
    for (int b = t; b < STATS_BLOCKS; b += 256) {
        s += partials[(size_t)c * STATS_BLOCKS + b];
        q += partials[(size_t)(128 + c) * STATS_BLOCKS + b];
    }
#pragma unroll
    for (int off = 32; off > 0; off >>= 1) {
        s += __shfl_xor(s, off);
        q += __shfl_xor(q, off);
    }
    __shared__ float ss[4], qq[4];
    const int lane = t & 63, w = t >> 6;
    if (lane == 0) { ss[w] = s; qq[w] = q; }
    __syncthreads();
    if (t == 0) {
        float S = ss[0] + ss[1] + ss[2] + ss[3];
        float Q = qq[0] + qq[1] + qq[2] + qq[3];
        float mean = S / n;
        float var = Q / n - mean * mean;
        float a = rsqrtf(var + 1e-5f) * gamma[c];
        ab[c] = a;
        ab[c + 128] = beta[c] - mean * a;
    }
}

// ---------------- BN apply ----------------
__global__ __launch_bounds__(256) void bn_apply_k(float* __restrict__ h,
    const float* __restrict__ ab, int total4)
{
    int i4 = blockIdx.x * blockDim.x + threadIdx.x;
    if (i4 >= total4) return;
    int cg = i4 & 31;
    float4 v = ((const float4*)h)[i4];
    float4 a = ((const float4*)ab)[cg];
    float4 b = ((const float4*)(ab + 128))[cg];
    ((float4*)h)[i4] = make_float4(v.x * a.x + b.x, v.y * a.y + b.y,
                                   v.z * a.z + b.z, v.w * a.w + b.w);
}

extern "C" void kernel_launch(void* const* d_in, const int* in_sizes, int n_in,
                              void* d_out, int out_size, void* d_ws, size_t ws_size,
                              hipStream_t stream)
{
    const float* x    = (const float*)d_in[0];
    const int*   ei   = (const int*)d_in[1];
    const float* ea   = (const float*)d_in[2];
    const float* Wl   = (const float*)d_in[3];
    const float* bl   = (const float*)d_in[4];
    const float* Wr   = (const float*)d_in[5];
    const float* br   = (const float*)d_in[6];
    const float* We   = (const float*)d_in[7];
    const float* att  = (const float*)d_in[8];
    const float* bias = (const float*)d_in[9];
    const float* gamma= (const float*)d_in[10];
    const float* beta = (const float*)d_in[11];
    float* out = (float*)d_out;

    const int n = in_sizes[0] / D;
    const int E = in_sizes[1] / 2;
    const int nb = (n + SCAN_CHUNK - 1) / SCAN_CHUNK;

    char* ws = (char*)d_ws;
    unsigned* xlb = (unsigned*)ws;                      // n*64 uints (bf16 xl)
    float* xr = (float*)(xlb + (size_t)n * 64);         // n*D floats
    int* deg = (int*)(xr + (size_t)n * D);              // n (becomes cursor)
    int* rowptr = deg + n;                              // n+1
    uintptr_t ep = ((uintptr_t)(rowptr + n + 1) + 7) & ~(uintptr_t)7;
    uint2* edges = (uint2*)ep;                          // E uint2
    float* partials = (float*)(edges + E);              // 256*STATS_BLOCKS
    int* bsum = (int*)(partials + 256 * STATS_BLOCKS);  // nb
    int* boff = bsum + nb;                              // nb
    float* ab = (float*)(boff + nb);                    // 256

    hipMemsetAsync(deg, 0, (size_t)n * 4, stream);

    dim3 gg((n + 31) / 32, 2);
    gemm_k<<<gg, 256, 0, stream>>>(x, Wl, bl, Wr, br, xlb, xr, n);
    hist_k<<<(E + 255) / 256, 256, 0, stream>>>(ei, deg, E);
    scan_sum_k<<<nb, 256, 0, stream>>>(deg, bsum, n);
    scan_off_k<<<1, 256, 0, stream>>>(bsum, boff, rowptr, nb, n);
    scan_fin_k<<<nb, 256, 0, stream>>>(deg, boff, rowptr, n);
    scatter_k<<<(E + 255) / 256, 256, 0, stream>>>(ei, ea, deg, edges, E);
    agg_k<<<(n + 3) / 4, 256, 0, stream>>>(xlb, xr, rowptr, edges, We, att, out, n);
    const int total4 = (n * D) / 4;
    gelu_stats_k<<<STATS_BLOCKS, 256, 0, stream>>>(x, bias, out, partials, total4);
    bn_reduce_params_k<<<128, 256, 0, stream>>>(partials, gamma, beta, ab, (float)n);
    bn_apply_k<<<(total4 + 255) / 256, 256, 0, stream>>>(out, ab, total4);
}

// Round 7
// 190.720 us; speedup vs baseline: 4.9486x; 1.1384x over previous
//
#include <hip/hip_runtime.h>
#include <math.h>

#define D 128
#define STATS_BLOCKS 512
#define SCAN_CHUNK 256

typedef __attribute__((ext_vector_type(8))) short short8;
typedef __attribute__((ext_vector_type(4))) float f32x4;

__device__ __forceinline__ unsigned short f2bf(float f) {
    unsigned u = __float_as_uint(f);
    unsigned r = (u + 0x7fff + ((u >> 16) & 1)) >> 16;   // RNE
    return (unsigned short)r;
}

// ---------------- pack Wl|Wr into fragment-major bf16 ----------------
// slot = ct*4+kt (ct 0..15: 0-7 Wl cols, 8-15 Wr cols); per slot 64 lanes x 8 bf16:
// element i of lane l = W[kt*32 + (l>>4)*8 + i][(ct&7)*16 + (l&15)]
__global__ __launch_bounds__(256) void pack_w_k(const float* __restrict__ Wl,
    const float* __restrict__ Wr, unsigned short* __restrict__ wpack)
{
    const int lane = threadIdx.x & 63;
    const int wv = threadIdx.x >> 6;
    const int slot = blockIdx.x * 4 + wv;     // grid 16 -> slots 0..63
    const int ct = slot >> 2;
    const int kt = slot & 3;
    const float* W = (ct < 8) ? Wl : Wr;
    const int cb = (ct & 7) * 16 + (lane & 15);
    const int kb = kt * 32 + (lane >> 4) * 8;
    unsigned short v[8];
#pragma unroll
    for (int i = 0; i < 8; i++) v[i] = f2bf(W[(size_t)(kb + i) * D + cb]);
    *(uint4*)(wpack + ((size_t)slot << 9) + lane * 8) = *(uint4*)v;
}

// ---------------- MFMA GEMM: xl(bf16 packed) = x@Wl+bl, xr(f32) = x@Wr+br ----------------
// one wave per 16-row tile; 64 MFMAs (16 col-tiles x 4 k-tiles)
__global__ __launch_bounds__(256) void gemm_mfma_k(const float* __restrict__ x,
    const unsigned short* __restrict__ wpack, const float* __restrict__ bl,
    const float* __restrict__ br, unsigned* __restrict__ xlb,
    float* __restrict__ xr, int n)
{
    const int lane = threadIdx.x & 63;
    const int wv = threadIdx.x >> 6;
    const int rt = blockIdx.x * 4 + wv;          // 16-row tile index
    if (rt * 16 >= n) return;
    const int r0 = rt * 16;
    const int ra = r0 + (lane & 15);             // this lane's A row
    const int r = ra < n ? ra : n - 1;           // clamp (n%16==0 normally)
    const int ko = (lane >> 4) * 8;              // k-octet base

    // A fragments: 8 consecutive k as bf16
    short8 a[4];
#pragma unroll
    for (int kt = 0; kt < 4; kt++) {
        const float* px = x + (size_t)r * D + kt * 32 + ko;
        float4 lo = *(const float4*)px;
        float4 hi = *(const float4*)(px + 4);
        short8 t;
        t[0] = (short)f2bf(lo.x); t[1] = (short)f2bf(lo.y);
        t[2] = (short)f2bf(lo.z); t[3] = (short)f2bf(lo.w);
        t[4] = (short)f2bf(hi.x); t[5] = (short)f2bf(hi.y);
        t[6] = (short)f2bf(hi.z); t[7] = (short)f2bf(hi.w);
        a[kt] = t;
    }

    f32x4 acc[16];
#pragma unroll
    for (int i = 0; i < 16; i++) acc[i] = (f32x4){0.f, 0.f, 0.f, 0.f};

#pragma unroll
    for (int kt = 0; kt < 4; kt++) {
#pragma unroll
        for (int ct = 0; ct < 16; ct++) {
            short8 b = *(const short8*)(wpack + (((size_t)(ct * 4 + kt)) << 9) + lane * 8);
            acc[ct] = __builtin_amdgcn_mfma_f32_16x16x32_bf16(a[kt], b, acc[ct], 0, 0, 0);
        }
    }

    const int colb = lane & 15;
    const int rbase = r0 + (lane >> 4) * 4;
    // Wr side -> xr (f32)
#pragma unroll
    for (int ct = 8; ct < 16; ct++) {
        const int c = (ct - 8) * 16 + colb;
        const float bb = br[c];
#pragma unroll
        for (int reg = 0; reg < 4; reg++) {
            const int row = rbase + reg;
            if (row < n) xr[(size_t)row * D + c] = acc[ct][reg] + bb;
        }
    }
    // Wl side -> xlb (bf16 pairs packed in uint)
#pragma unroll
    for (int ct = 0; ct < 8; ct++) {
        const int c = ct * 16 + colb;
        const float bb = bl[c];
#pragma unroll
        for (int reg = 0; reg < 4; reg++) {
            unsigned mybf = f2bf(acc[ct][reg] + bb);
            unsigned other = (unsigned)__shfl_xor((int)mybf, 1);
            if ((lane & 1) == 0) {
                const int row = rbase + reg;
                if (row < n) xlb[(size_t)row * 64 + (c >> 1)] = mybf | (other << 16);
            }
        }
    }
}

// ---------------- CSR build: histogram ----------------
__global__ __launch_bounds__(256) void hist_k(const int* __restrict__ ei,
    int* __restrict__ deg, int E)
{
    int e = blockIdx.x * blockDim.x + threadIdx.x;
    if (e < E) atomicAdd(&deg[ei[E + e]], 1);
}

// ---------------- hierarchical scan, stage 1: per-block chunk sums ----------------
__global__ __launch_bounds__(256) void scan_sum_k(const int* __restrict__ deg,
    int* __restrict__ bsum, int n)
{
    const int t = threadIdx.x;
    const int i = blockIdx.x * SCAN_CHUNK + t;
    int s = (i < n) ? deg[i] : 0;
#pragma unroll
    for (int off = 32; off > 0; off >>= 1) s += __shfl_xor(s, off);
    __shared__ int ws_[4];
    const int lane = t & 63, w = t >> 6;
    if (lane == 0) ws_[w] = s;
    __syncthreads();
    if (t == 0) bsum[blockIdx.x] = ws_[0] + ws_[1] + ws_[2] + ws_[3];
}

// ---------------- stage 2: exclusive scan of block sums (nb <= 256) ----------------
__global__ __launch_bounds__(256) void scan_off_k(const int* __restrict__ bsum,
    int* __restrict__ boff, int* __restrict__ rowptr, int nb, int n)
{
    const int t = threadIdx.x;
    int v = (t < nb) ? bsum[t] : 0;
    const int lane = t & 63, w = t >> 6;
    int inc = v;
#pragma unroll
    for (int off = 1; off < 64; off <<= 1) {
        int u = __shfl_up(inc, off);
        if (lane >= off) inc += u;
    }
    __shared__ int wsum[4], wpre[4];
    if (lane == 63) wsum[w] = inc;
    __syncthreads();
    if (t == 0) {
        int r = 0;
#pragma unroll
        for (int j = 0; j < 4; j++) { wpre[j] = r; r += wsum[j]; }
        rowptr[n] = r;
    }
    __syncthreads();
    if (t < nb) boff[t] = inc - v + wpre[w];
}

// ---------------- stage 3: in-block exclusive scan + offset ----------------
__global__ __launch_bounds__(256) void scan_fin_k(int* __restrict__ deg,
    const int* __restrict__ boff, int* __restrict__ rowptr, int n)
{
    const int t = threadIdx.x;
    const int i = blockIdx.x * SCAN_CHUNK + t;
    int v = (i < n) ? deg[i] : 0;
    const int lane = t & 63, w = t >> 6;
    int inc = v;
#pragma unroll
    for (int off = 1; off < 64; off <<= 1) {
        int u = __shfl_up(inc, off);
        if (lane >= off) inc += u;
    }
    __shared__ int wsum[4], wpre[4];
    if (lane == 63) wsum[w] = inc;
    __syncthreads();
    if (t == 0) {
        int r = 0;
#pragma unroll
        for (int j = 0; j < 4; j++) { wpre[j] = r; r += wsum[j]; }
    }
    __syncthreads();
    if (i < n) {
        int ex = inc - v + wpre[w] + boff[blockIdx.x];
        rowptr[i] = ex;
        deg[i] = ex;                 // scatter cursor
    }
}

// ---------------- CSR build: scatter {src, ea} pairs into dst-grouped order ----------------
__global__ __launch_bounds__(256) void scatter_k(const int* __restrict__ ei,
    const float* __restrict__ ea, int* __restrict__ cursor,
    uint2* __restrict__ edges, int E)
{
    int e = blockIdx.x * blockDim.x + threadIdx.x;
    if (e >= E) return;
    int dst = ei[E + e];
    int pos = atomicAdd(&cursor[dst], 1);
    edges[pos] = make_uint2((unsigned)ei[e], __float_as_uint(ea[e]));
}

// ---------------- fused edge logits + online softmax + aggregate ----------------
// one 64-lane wave per destination node; lane owns 2 feature columns.
// 4 edges per iteration: independent shfl-reduce chains (4-way ILP),
// one group-max rescale, prefetch of the next group during compute.
__global__ __launch_bounds__(256) void agg_k(const unsigned* __restrict__ xlb,
    const float* __restrict__ xr, const int* __restrict__ rowptr,
    const uint2* __restrict__ edges, const float* __restrict__ We,
    const float* __restrict__ att, float* __restrict__ out, int n)
{
    int wave = threadIdx.x >> 6;
    int lane = threadIdx.x & 63;
    int v = blockIdx.x * 4 + wave;
    if (v >= n) return;
    int beg = rowptr[v];
    int end = rowptr[v + 1];
    int c = lane * 2;
    float2 xrv = *(const float2*)(xr + (size_t)v * D + c);
    float2 wev = *(const float2*)(We + c);
    float2 atv = *(const float2*)(att + c);

    float m = -INFINITY, s = 0.f, acc0 = 0.f, acc1 = 0.f;

    uint2 e2[4]; unsigned xb[4];
    if (beg < end) {
#pragma unroll
        for (int e = 0; e < 4; e++) {
            int jj = beg + e < end ? beg + e : end - 1;
            e2[e] = edges[jj];
            xb[e] = xlb[(size_t)e2[e].x * 64 + lane];
        }
    }
    for (int j = beg; j < end; j += 4) {
        // prefetch next group (clamped; redundant on last iter)
        int jn = j + 4;
        uint2 e2n[4]; unsigned xbn[4];
#pragma unroll
        for (int e = 0; e < 4; e++) {
            int jj = jn + e < end ? jn + e : end - 1;
            e2n[e] = edges[jj];
            xbn[e] = xlb[(size_t)e2n[e].x * 64 + lane];
        }

        float p[4], xv0[4], xv1[4];
#pragma unroll
        for (int e = 0; e < 4; e++) {
            float eav = __uint_as_float(e2[e].y);
            xv0[e] = __uint_as_float(xb[e] << 16);
            xv1[e] = __uint_as_float(xb[e] & 0xffff0000u);
            float m0 = xv0[e] + xrv.x + eav * wev.x;
            float m1 = xv1[e] + xrv.y + eav * wev.y;
            m0 = m0 > 0.f ? m0 : 0.2f * m0;
            m1 = m1 > 0.f ? m1 : 0.2f * m1;
            p[e] = m0 * atv.x + m1 * atv.y;
        }
        // 4 interleaved butterfly reductions (independent -> pipelined)
#pragma unroll
        for (int off = 32; off > 0; off >>= 1) {
#pragma unroll
            for (int e = 0; e < 4; e++) p[e] += __shfl_xor(p[e], off);
        }
        // mask tail edges
#pragma unroll
        for (int e = 1; e < 4; e++) if (j + e >= end) p[e] = -INFINITY;

        float pm = fmaxf(fmaxf(p[0], p[1]), fmaxf(p[2], p[3]));
        // wave-uniform branch: p[], m identical across lanes
        if (pm > m) {
            float sc = __expf(m - pm);   // first group: exp(-inf)=0
            s *= sc; acc0 *= sc; acc1 *= sc;
            m = pm;
        }
#pragma unroll
        for (int e = 0; e < 4; e++) {
            float w = __expf(p[e] - m);  // masked -> exp(-inf)=0
            s += w;
            acc0 += w * xv0[e];
            acc1 += w * xv1[e];
        }
#pragma unroll
        for (int e = 0; e < 4; e++) { e2[e] = e2n[e]; xb[e] = xbn[e]; }
    }
    float inv = 1.f / (s + 1e-16f);   // deg==0 -> acc=0 -> out=0
    *(float2*)(out + (size_t)v * D + c) = make_float2(acc0 * inv, acc1 * inv);
}

// ---------------- residual + GELU(erf) + BN stats (atomic-free) ----------------
__global__ __launch_bounds__(256) void gelu_stats_k(const float* __restrict__ x,
    const float* __restrict__ bias, float* __restrict__ h,
    float* __restrict__ partials, int total4)
{
    const int t = threadIdx.x;
    const int c0 = (t & 31) * 4;
    const float4 bv = *(const float4*)&bias[c0];
    float sum[4] = {0.f, 0.f, 0.f, 0.f}, sq[4] = {0.f, 0.f, 0.f, 0.f};
    const int stride = gridDim.x * blockDim.x;
    for (int i4 = blockIdx.x * blockDim.x + t; i4 < total4; i4 += stride) {
        float4 g4 = ((const float4*)h)[i4];
        float4 xv = ((const float4*)x)[i4];
        float hv[4] = {xv.x + g4.x + bv.x, xv.y + g4.y + bv.y,
                       xv.z + g4.z + bv.z, xv.w + g4.w + bv.w};
        float res[4];
#pragma unroll
        for (int j = 0; j < 4; j++) {
            float ge = 0.5f * hv[j] * (1.f + erff(hv[j] * 0.70710678118654752f));
            res[j] = ge;
            sum[j] += ge;
            sq[j] += ge * ge;
        }
        ((float4*)h)[i4] = make_float4(res[0], res[1], res[2], res[3]);
    }
    __shared__ float red[8][128];
    const int slot = t >> 5;
#pragma unroll
    for (int j = 0; j < 4; j++) red[slot][c0 + j] = sum[j];
    __syncthreads();
    if (t < 128) {
        float tot = 0.f;
#pragma unroll
        for (int s2 = 0; s2 < 8; s2++) tot += red[s2][t];
        partials[(size_t)t * STATS_BLOCKS + blockIdx.x] = tot;
    }
    __syncthreads();
#pragma unroll
    for (int j = 0; j < 4; j++) red[slot][c0 + j] = sq[j];
    __syncthreads();
    if (t < 128) {
        float tot = 0.f;
#pragma unroll
        for (int s2 = 0; s2 < 8; s2++) tot += red[s2][t];
        partials[(size_t)(128 + t) * STATS_BLOCKS + blockIdx.x] = tot;
    }
}

// ---------------- reduce partials + fold BN params ----------------
__global__ __launch_bounds__(256) void bn_reduce_params_k(const float* __restrict__ partials,
    const float* __restrict__ gamma, const float* __restrict__ beta,
    float* __restrict__ ab, float n)
{
    const int c = blockIdx.x;      // 0..127
    const int t = threadIdx.x;     // 256
    float s = 0.f, q = 0.f;
    for (int b = t; b < STATS_BLOCKS; b += 256) {
        s += partials[(size_t)c * STATS_BLOCKS + b];
        q += partials[(size_t)(128 + c) * STATS_BLOCKS + b];
    }
#pragma unroll
    for (int off = 32; off > 0; off >>= 1) {
        s += __shfl_xor(s, off);
        q += __shfl_xor(q, off);
    }
    __shared__ float ss[4], qq[4];
    const int lane = t & 63, w = t >> 6;
    if (lane == 0) { ss[w] = s; qq[w] = q; }
    __syncthreads();
    if (t == 0) {
        float S = ss[0] + ss[1] + ss[2] + ss[3];
        float Q = qq[0] + qq[1] + qq[2] + qq[3];
        float mean = S / n;
        float var = Q / n - mean * mean;
        float a = rsqrtf(var + 1e-5f) * gamma[c];
        ab[c] = a;
        ab[c + 128] = beta[c] - mean * a;
    }
}

// ---------------- BN apply ----------------
__global__ __launch_bounds__(256) void bn_apply_k(float* __restrict__ h,
    const float* __restrict__ ab, int total4)
{
    int i4 = blockIdx.x * blockDim.x + threadIdx.x;
    if (i4 >= total4) return;
    int cg = i4 & 31;
    float4 v = ((const float4*)h)[i4];
    float4 a = ((const float4*)ab)[cg];
    float4 b = ((const float4*)(ab + 128))[cg];
    ((float4*)h)[i4] = make_float4(v.x * a.x + b.x, v.y * a.y + b.y,
                                   v.z * a.z + b.z, v.w * a.w + b.w);
}

extern "C" void kernel_launch(void* const* d_in, const int* in_sizes, int n_in,
                              void* d_out, int out_size, void* d_ws, size_t ws_size,
                              hipStream_t stream)
{
    const float* x    = (const float*)d_in[0];
    const int*   ei   = (const int*)d_in[1];
    const float* ea   = (const float*)d_in[2];
    const float* Wl   = (const float*)d_in[3];
    const float* bl   = (const float*)d_in[4];
    const float* Wr   = (const float*)d_in[5];
    const float* br   = (const float*)d_in[6];
    const float* We   = (const float*)d_in[7];
    const float* att  = (const float*)d_in[8];
    const float* bias = (const float*)d_in[9];
    const float* gamma= (const float*)d_in[10];
    const float* beta = (const float*)d_in[11];
    float* out = (float*)d_out;

    const int n = in_sizes[0] / D;
    const int E = in_sizes[1] / 2;
    const int nb = (n + SCAN_CHUNK - 1) / SCAN_CHUNK;

    char* ws = (char*)d_ws;
    unsigned short* wpack = (unsigned short*)ws;        // 32768 bf16 (64 KB)
    unsigned* xlb = (unsigned*)(ws + 65536);            // n*64 uints (bf16 xl)
    float* xr = (float*)(xlb + (size_t)n * 64);         // n*D floats
    int* deg = (int*)(xr + (size_t)n * D);              // n (becomes cursor)
    int* rowptr = deg + n;                              // n+1
    uintptr_t ep = ((uintptr_t)(rowptr + n + 1) + 7) & ~(uintptr_t)7;
    uint2* edges = (uint2*)ep;                          // E uint2
    float* partials = (float*)(edges + E);              // 256*STATS_BLOCKS
    int* bsum = (int*)(partials + 256 * STATS_BLOCKS);  // nb
    int* boff = bsum + nb;                              // nb
    float* ab = (float*)(boff + nb);                    // 256

    hipMemsetAsync(deg, 0, (size_t)n * 4, stream);

    pack_w_k<<<16, 256, 0, stream>>>(Wl, Wr, wpack);
    const int nrt = (n + 15) / 16;
    gemm_mfma_k<<<(nrt + 3) / 4, 256, 0, stream>>>(x, wpack, bl, br, xlb, xr, n);
    hist_k<<<(E + 255) / 256, 256, 0, stream>>>(ei, deg, E);
    scan_sum_k<<<nb, 256, 0, stream>>>(deg, bsum, n);
    scan_off_k<<<1, 256, 0, stream>>>(bsum, boff, rowptr, nb, n);
    scan_fin_k<<<nb, 256, 0, stream>>>(deg, boff, rowptr, n);
    scatter_k<<<(E + 255) / 256, 256, 0, stream>>>(ei, ea, deg, edges, E);
    agg_k<<<(n + 3) / 4, 256, 0, stream>>>(xlb, xr, rowptr, edges, We, att, out, n);
    const int total4 = (n * D) / 4;
    gelu_stats_k<<<STATS_BLOCKS, 256, 0, stream>>>(x, bias, out, partials, total4);
    bn_reduce_params_k<<<128, 256, 0, stream>>>(partials, gamma, beta, ab, (float)n);
    bn_apply_k<<<(total4 + 255) / 256, 256, 0, stream>>>(out, ab, total4);
}

// Round 8
// 173.689 us; speedup vs baseline: 5.4339x; 1.0981x over previous
//
#include <hip/hip_runtime.h>
#include <math.h>

#define D 128
#define STATS_BLOCKS 512
#define SCAN_CHUNK 256

typedef __attribute__((ext_vector_type(8))) short short8;
typedef __attribute__((ext_vector_type(4))) float f32x4;

__device__ __forceinline__ unsigned short f2bf(float f) {
    unsigned u = __float_as_uint(f);
    unsigned r = (u + 0x7fff + ((u >> 16) & 1)) >> 16;   // RNE
    return (unsigned short)r;
}

// ---------------- pack Wl|Wr into fragment-major bf16 ----------------
__global__ __launch_bounds__(256) void pack_w_k(const float* __restrict__ Wl,
    const float* __restrict__ Wr, unsigned short* __restrict__ wpack)
{
    const int lane = threadIdx.x & 63;
    const int wv = threadIdx.x >> 6;
    const int slot = blockIdx.x * 4 + wv;     // grid 16 -> slots 0..63
    const int ct = slot >> 2;
    const int kt = slot & 3;
    const float* W = (ct < 8) ? Wl : Wr;
    const int cb = (ct & 7) * 16 + (lane & 15);
    const int kb = kt * 32 + (lane >> 4) * 8;
    unsigned short v[8];
#pragma unroll
    for (int i = 0; i < 8; i++) v[i] = f2bf(W[(size_t)(kb + i) * D + cb]);
    *(uint4*)(wpack + ((size_t)slot << 9) + lane * 8) = *(uint4*)v;
}

// ---------------- MFMA GEMM: xl(bf16 packed) = x@Wl+bl, xr(f32) = x@Wr+br ----------------
__global__ __launch_bounds__(256) void gemm_mfma_k(const float* __restrict__ x,
    const unsigned short* __restrict__ wpack, const float* __restrict__ bl,
    const float* __restrict__ br, unsigned* __restrict__ xlb,
    float* __restrict__ xr, int n)
{
    const int lane = threadIdx.x & 63;
    const int wv = threadIdx.x >> 6;
    const int rt = blockIdx.x * 4 + wv;          // 16-row tile index
    if (rt * 16 >= n) return;
    const int r0 = rt * 16;
    const int ra = r0 + (lane & 15);
    const int r = ra < n ? ra : n - 1;
    const int ko = (lane >> 4) * 8;

    short8 a[4];
#pragma unroll
    for (int kt = 0; kt < 4; kt++) {
        const float* px = x + (size_t)r * D + kt * 32 + ko;
        float4 lo = *(const float4*)px;
        float4 hi = *(const float4*)(px + 4);
        short8 t;
        t[0] = (short)f2bf(lo.x); t[1] = (short)f2bf(lo.y);
        t[2] = (short)f2bf(lo.z); t[3] = (short)f2bf(lo.w);
        t[4] = (short)f2bf(hi.x); t[5] = (short)f2bf(hi.y);
        t[6] = (short)f2bf(hi.z); t[7] = (short)f2bf(hi.w);
        a[kt] = t;
    }

    f32x4 acc[16];
#pragma unroll
    for (int i = 0; i < 16; i++) acc[i] = (f32x4){0.f, 0.f, 0.f, 0.f};

#pragma unroll
    for (int kt = 0; kt < 4; kt++) {
#pragma unroll
        for (int ct = 0; ct < 16; ct++) {
            short8 b = *(const short8*)(wpack + (((size_t)(ct * 4 + kt)) << 9) + lane * 8);
            acc[ct] = __builtin_amdgcn_mfma_f32_16x16x32_bf16(a[kt], b, acc[ct], 0, 0, 0);
        }
    }

    const int colb = lane & 15;
    const int rbase = r0 + (lane >> 4) * 4;
#pragma unroll
    for (int ct = 8; ct < 16; ct++) {
        const int c = (ct - 8) * 16 + colb;
        const float bb = br[c];
#pragma unroll
        for (int reg = 0; reg < 4; reg++) {
            const int row = rbase + reg;
            if (row < n) xr[(size_t)row * D + c] = acc[ct][reg] + bb;
        }
    }
#pragma unroll
    for (int ct = 0; ct < 8; ct++) {
        const int c = ct * 16 + colb;
        const float bb = bl[c];
#pragma unroll
        for (int reg = 0; reg < 4; reg++) {
            unsigned mybf = f2bf(acc[ct][reg] + bb);
            unsigned other = (unsigned)__shfl_xor((int)mybf, 1);
            if ((lane & 1) == 0) {
                const int row = rbase + reg;
                if (row < n) xlb[(size_t)row * 64 + (c >> 1)] = mybf | (other << 16);
            }
        }
    }
}

// ---------------- CSR build: histogram ----------------
__global__ __launch_bounds__(256) void hist_k(const int* __restrict__ ei,
    int* __restrict__ deg, int E)
{
    int e = blockIdx.x * blockDim.x + threadIdx.x;
    if (e < E) atomicAdd(&deg[ei[E + e]], 1);
}

// ---------------- hierarchical scan, stage 1: per-block chunk sums ----------------
__global__ __launch_bounds__(256) void scan_sum_k(const int* __restrict__ deg,
    int* __restrict__ bsum, int n)
{
    const int t = threadIdx.x;
    const int i = blockIdx.x * SCAN_CHUNK + t;
    int s = (i < n) ? deg[i] : 0;
#pragma unroll
    for (int off = 32; off > 0; off >>= 1) s += __shfl_xor(s, off);
    __shared__ int ws_[4];
    const int lane = t & 63, w = t >> 6;
    if (lane == 0) ws_[w] = s;
    __syncthreads();
    if (t == 0) bsum[blockIdx.x] = ws_[0] + ws_[1] + ws_[2] + ws_[3];
}

// ---------------- stage 2: exclusive scan of block sums (nb <= 256) ----------------
__global__ __launch_bounds__(256) void scan_off_k(const int* __restrict__ bsum,
    int* __restrict__ boff, int* __restrict__ rowptr, int nb, int n)
{
    const int t = threadIdx.x;
    int v = (t < nb) ? bsum[t] : 0;
    const int lane = t & 63, w = t >> 6;
    int inc = v;
#pragma unroll
    for (int off = 1; off < 64; off <<= 1) {
        int u = __shfl_up(inc, off);
        if (lane >= off) inc += u;
    }
    __shared__ int wsum[4], wpre[4];
    if (lane == 63) wsum[w] = inc;
    __syncthreads();
    if (t == 0) {
        int r = 0;
#pragma unroll
        for (int j = 0; j < 4; j++) { wpre[j] = r; r += wsum[j]; }
        rowptr[n] = r;
    }
    __syncthreads();
    if (t < nb) boff[t] = inc - v + wpre[w];
}

// ---------------- stage 3: in-block exclusive scan + offset ----------------
__global__ __launch_bounds__(256) void scan_fin_k(int* __restrict__ deg,
    const int* __restrict__ boff, int* __restrict__ rowptr, int n)
{
    const int t = threadIdx.x;
    const int i = blockIdx.x * SCAN_CHUNK + t;
    int v = (i < n) ? deg[i] : 0;
    const int lane = t & 63, w = t >> 6;
    int inc = v;
#pragma unroll
    for (int off = 1; off < 64; off <<= 1) {
        int u = __shfl_up(inc, off);
        if (lane >= off) inc += u;
    }
    __shared__ int wsum[4], wpre[4];
    if (lane == 63) wsum[w] = inc;
    __syncthreads();
    if (t == 0) {
        int r = 0;
#pragma unroll
        for (int j = 0; j < 4; j++) { wpre[j] = r; r += wsum[j]; }
    }
    __syncthreads();
    if (i < n) {
        int ex = inc - v + wpre[w] + boff[blockIdx.x];
        rowptr[i] = ex;
        deg[i] = ex;                 // scatter cursor
    }
}

// ---------------- CSR build: scatter {src, ea} pairs into dst-grouped order ----------------
__global__ __launch_bounds__(256) void scatter_k(const int* __restrict__ ei,
    const float* __restrict__ ea, int* __restrict__ cursor,
    uint2* __restrict__ edges, int E)
{
    int e = blockIdx.x * blockDim.x + threadIdx.x;
    if (e >= E) return;
    int dst = ei[E + e];
    int pos = atomicAdd(&cursor[dst], 1);
    edges[pos] = make_uint2((unsigned)ei[e], __float_as_uint(ea[e]));
}

// ---------------- fused edge logits + online softmax + aggregate ----------------
// wave = 1 dst node, split into 4 groups of 16 lanes; group g walks edges
// beg+g, beg+g+4, ... Lane owns 8 features (one uint4 of the bf16 row).
// Logit reduce = 4-step butterfly within the 16-lane group (1 shfl-instr/edge
// serves 4 edges). Branchless online softmax per group; 2-step softmax-merge
// of the 4 group states at the end.
__global__ __launch_bounds__(256) void agg_k(const unsigned* __restrict__ xlb,
    const float* __restrict__ xr, const int* __restrict__ rowptr,
    const uint2* __restrict__ edges, const float* __restrict__ We,
    const float* __restrict__ att, float* __restrict__ out, int n)
{
    const int wave = threadIdx.x >> 6;
    const int lane = threadIdx.x & 63;
    const int g = lane >> 4;          // group 0..3
    const int li = lane & 15;         // lane in group: features li*8..li*8+7
    const int v = blockIdx.x * 4 + wave;
    if (v >= n) return;
    const int beg = rowptr[v];
    const int end = rowptr[v + 1];

    float xrv[8], wev[8], atv[8];
    {
        const int f0 = li * 8;
        float4 a0 = *(const float4*)(xr + (size_t)v * D + f0);
        float4 a1 = *(const float4*)(xr + (size_t)v * D + f0 + 4);
        xrv[0]=a0.x; xrv[1]=a0.y; xrv[2]=a0.z; xrv[3]=a0.w;
        xrv[4]=a1.x; xrv[5]=a1.y; xrv[6]=a1.z; xrv[7]=a1.w;
        float4 w0 = *(const float4*)(We + f0);
        float4 w1 = *(const float4*)(We + f0 + 4);
        wev[0]=w0.x; wev[1]=w0.y; wev[2]=w0.z; wev[3]=w0.w;
        wev[4]=w1.x; wev[5]=w1.y; wev[6]=w1.z; wev[7]=w1.w;
        float4 t0 = *(const float4*)(att + f0);
        float4 t1 = *(const float4*)(att + f0 + 4);
        atv[0]=t0.x; atv[1]=t0.y; atv[2]=t0.z; atv[3]=t0.w;
        atv[4]=t1.x; atv[5]=t1.y; atv[6]=t1.z; atv[7]=t1.w;
    }

    float m = -1e30f, s = 0.f;
    float acc[8];
#pragma unroll
    for (int k = 0; k < 8; k++) acc[k] = 0.f;

    int j = beg + g;
    uint2 e2 = make_uint2(0u, 0u);
    uint4 xb4 = make_uint4(0u, 0u, 0u, 0u);
    if (j < end) {
        e2 = edges[j];
        xb4 = *(const uint4*)(xlb + (size_t)e2.x * 64 + li * 4);
    }
    while (j < end) {
        const int jn = j + 4;
        const int jc = jn < end ? jn : end - 1;     // clamped prefetch
        uint2 e2n = edges[jc];
        uint4 xbn = *(const uint4*)(xlb + (size_t)e2n.x * 64 + li * 4);

        const float eav = __uint_as_float(e2.y);
        float xv[8];
        xv[0] = __uint_as_float(xb4.x << 16); xv[1] = __uint_as_float(xb4.x & 0xffff0000u);
        xv[2] = __uint_as_float(xb4.y << 16); xv[3] = __uint_as_float(xb4.y & 0xffff0000u);
        xv[4] = __uint_as_float(xb4.z << 16); xv[5] = __uint_as_float(xb4.z & 0xffff0000u);
        xv[6] = __uint_as_float(xb4.w << 16); xv[7] = __uint_as_float(xb4.w & 0xffff0000u);

        float p = 0.f;
#pragma unroll
        for (int k = 0; k < 8; k++) {
            float t = fmaf(eav, wev[k], xrv[k]) + xv[k];
            t = fmaxf(t, 0.2f * t);                 // leaky relu
            p = fmaf(t, atv[k], p);
        }
        // 4-step butterfly within the 16-lane group
#pragma unroll
        for (int off = 8; off >= 1; off >>= 1) p += __shfl_xor(p, off);

        // branchless online softmax (m starts at -1e30: exp(-1e30-p)==0)
        const float pm = fmaxf(m, p);
        const float sc = __expf(m - pm);
        const float w  = __expf(p - pm);
        s = s * sc + w;
#pragma unroll
        for (int k = 0; k < 8; k++) acc[k] = fmaf(acc[k], sc, w * xv[k]);
        m = pm;

        e2 = e2n; xb4 = xbn; j = jn;
    }

    // merge the 4 group states (lanes l, l^16, l^32 hold same features)
#pragma unroll
    for (int off = 16; off <= 32; off <<= 1) {
        const float mo = __shfl_xor(m, off);
        const float so = __shfl_xor(s, off);
        const float pm = fmaxf(m, mo);
        const float sa = __expf(m - pm);    // both empty: exp(0)=1, s stays 0
        const float sb = __expf(mo - pm);
        s = s * sa + so * sb;
#pragma unroll
        for (int k = 0; k < 8; k++)
            acc[k] = acc[k] * sa + __shfl_xor(acc[k], off) * sb;
        m = pm;
    }

    if (g == 0) {
        const float inv = 1.f / (s + 1e-16f);       // deg==0 -> acc=0 -> out=0
        const int f0 = li * 8;
        float4 o0 = make_float4(acc[0]*inv, acc[1]*inv, acc[2]*inv, acc[3]*inv);
        float4 o1 = make_float4(acc[4]*inv, acc[5]*inv, acc[6]*inv, acc[7]*inv);
        *(float4*)(out + (size_t)v * D + f0) = o0;
        *(float4*)(out + (size_t)v * D + f0 + 4) = o1;
    }
}

// ---------------- residual + GELU(erf) + BN stats (atomic-free) ----------------
__global__ __launch_bounds__(256) void gelu_stats_k(const float* __restrict__ x,
    const float* __restrict__ bias, float* __restrict__ h,
    float* __restrict__ partials, int total4)
{
    const int t = threadIdx.x;
    const int c0 = (t & 31) * 4;
    const float4 bv = *(const float4*)&bias[c0];
    float sum[4] = {0.f, 0.f, 0.f, 0.f}, sq[4] = {0.f, 0.f, 0.f, 0.f};
    const int stride = gridDim.x * blockDim.x;
    for (int i4 = blockIdx.x * blockDim.x + t; i4 < total4; i4 += stride) {
        float4 g4 = ((const float4*)h)[i4];
        float4 xv = ((const float4*)x)[i4];
        float hv[4] = {xv.x + g4.x + bv.x, xv.y + g4.y + bv.y,
                       xv.z + g4.z + bv.z, xv.w + g4.w + bv.w};
        float res[4];
#pragma unroll
        for (int j = 0; j < 4; j++) {
            float ge = 0.5f * hv[j] * (1.f + erff(hv[j] * 0.70710678118654752f));
            res[j] = ge;
            sum[j] += ge;
            sq[j] += ge * ge;
        }
        ((float4*)h)[i4] = make_float4(res[0], res[1], res[2], res[3]);
    }
    __shared__ float red[8][128];
    const int slot = t >> 5;
#pragma unroll
    for (int j = 0; j < 4; j++) red[slot][c0 + j] = sum[j];
    __syncthreads();
    if (t < 128) {
        float tot = 0.f;
#pragma unroll
        for (int s2 = 0; s2 < 8; s2++) tot += red[s2][t];
        partials[(size_t)t * STATS_BLOCKS + blockIdx.x] = tot;
    }
    __syncthreads();
#pragma unroll
    for (int j = 0; j < 4; j++) red[slot][c0 + j] = sq[j];
    __syncthreads();
    if (t < 128) {
        float tot = 0.f;
#pragma unroll
        for (int s2 = 0; s2 < 8; s2++) tot += red[s2][t];
        partials[(size_t)(128 + t) * STATS_BLOCKS + blockIdx.x] = tot;
    }
}

// ---------------- reduce partials + fold BN params ----------------
__global__ __launch_bounds__(256) void bn_reduce_params_k(const float* __restrict__ partials,
    const float* __restrict__ gamma, const float* __restrict__ beta,
    float* __restrict__ ab, float n)
{
    const int c = blockIdx.x;      // 0..127
    const int t = threadIdx.x;     // 256
    float s = 0.f, q = 0.f;
    for (int b = t; b < STATS_BLOCKS; b += 256) {
        s += partials[(size_t)c * STATS_BLOCKS + b];
        q += partials[(size_t)(128 + c) * STATS_BLOCKS + b];
    }
#pragma unroll
    for (int off = 32; off > 0; off >>= 1) {
        s += __shfl_xor(s, off);
        q += __shfl_xor(q, off);
    }
    __shared__ float ss[4], qq[4];
    const int lane = t & 63, w = t >> 6;
    if (lane == 0) { ss[w] = s; qq[w] = q; }
    __syncthreads();
    if (t == 0) {
        float S = ss[0] + ss[1] + ss[2] + ss[3];
        float Q = qq[0] + qq[1] + qq[2] + qq[3];
        float mean = S / n;
        float var = Q / n - mean * mean;
        float a = rsqrtf(var + 1e-5f) * gamma[c];
        ab[c] = a;
        ab[c + 128] = beta[c] - mean * a;
    }
}

// ---------------- BN apply ----------------
__global__ __launch_bounds__(256) void bn_apply_k(float* __restrict__ h,
    const float* __restrict__ ab, int total4)
{
    int i4 = blockIdx.x * blockDim.x + threadIdx.x;
    if (i4 >= total4) return;
    int cg = i4 & 31;
    float4 v = ((const float4*)h)[i4];
    float4 a = ((const float4*)ab)[cg];
    float4 b = ((const float4*)(ab + 128))[cg];
    ((float4*)h)[i4] = make_float4(v.x * a.x + b.x, v.y * a.y + b.y,
                                   v.z * a.z + b.z, v.w * a.w + b.w);
}

extern "C" void kernel_launch(void* const* d_in, const int* in_sizes, int n_in,
                              void* d_out, int out_size, void* d_ws, size_t ws_size,
                              hipStream_t stream)
{
    const float* x    = (const float*)d_in[0];
    const int*   ei   = (const int*)d_in[1];
    const float* ea   = (const float*)d_in[2];
    const float* Wl   = (const float*)d_in[3];
    const float* bl   = (const float*)d_in[4];
    const float* Wr   = (const float*)d_in[5];
    const float* br   = (const float*)d_in[6];
    const float* We   = (const float*)d_in[7];
    const float* att  = (const float*)d_in[8];
    const float* bias = (const float*)d_in[9];
    const float* gamma= (const float*)d_in[10];
    const float* beta = (const float*)d_in[11];
    float* out = (float*)d_out;

    const int n = in_sizes[0] / D;
    const int E = in_sizes[1] / 2;
    const int nb = (n + SCAN_CHUNK - 1) / SCAN_CHUNK;

    char* ws = (char*)d_ws;
    unsigned short* wpack = (unsigned short*)ws;        // 32768 bf16 (64 KB)
    unsigned* xlb = (unsigned*)(ws + 65536);            // n*64 uints (bf16 xl)
    float* xr = (float*)(xlb + (size_t)n * 64);         // n*D floats
    int* deg = (int*)(xr + (size_t)n * D);              // n (becomes cursor)
    int* rowptr = deg + n;                              // n+1
    uintptr_t ep = ((uintptr_t)(rowptr + n + 1) + 7) & ~(uintptr_t)7;
    uint2* edges = (uint2*)ep;                          // E uint2
    float* partials = (float*)(edges + E);              // 256*STATS_BLOCKS
    int* bsum = (int*)(partials + 256 * STATS_BLOCKS);  // nb
    int* boff = bsum + nb;                              // nb
    float* ab = (float*)(boff + nb);                    // 256

    hipMemsetAsync(deg, 0, (size_t)n * 4, stream);

    pack_w_k<<<16, 256, 0, stream>>>(Wl, Wr, wpack);
    const int nrt = (n + 15) / 16;
    gemm_mfma_k<<<(nrt + 3) / 4, 256, 0, stream>>>(x, wpack, bl, br, xlb, xr, n);
    hist_k<<<(E + 255) / 256, 256, 0, stream>>>(ei, deg, E);
    scan_sum_k<<<nb, 256, 0, stream>>>(deg, bsum, n);
    scan_off_k<<<1, 256, 0, stream>>>(bsum, boff, rowptr, nb, n);
    scan_fin_k<<<nb, 256, 0, stream>>>(deg, boff, rowptr, n);
    scatter_k<<<(E + 255) / 256, 256, 0, stream>>>(ei, ea, deg, edges, E);
    agg_k<<<(n + 3) / 4, 256, 0, stream>>>(xlb, xr, rowptr, edges, We, att, out, n);
    const int total4 = (n * D) / 4;
    gelu_stats_k<<<STATS_BLOCKS, 256, 0, stream>>>(x, bias, out, partials, total4);
    bn_reduce_params_k<<<128, 256, 0, stream>>>(partials, gamma, beta, ab, (float)n);
    bn_apply_k<<<(total4 + 255) / 256, 256, 0, stream>>>(out, ab, total4);
}